// Round 9
// baseline (862.445 us; speedup 1.0000x reference)
//
#include <hip/hip_runtime.h>
#include <hip/hip_bf16.h>

#define NN 100000
#define NE 1600000
#define EP (NE + NN)      // 1700000 edges incl self loops
#define NH 4
#define NC 32
#define DD 128
#define NG 64
#define NIN 7

#define BSH 9                       // bucket = dst >> 9 (512 nodes/bucket)
#define NBUK ((NN + 511) >> BSH)    // 196
#define SEGCAP 9600                 // CSR segment cap (mean 8704, sigma ~90)

typedef __hip_bfloat16 bf16;
typedef __attribute__((ext_vector_type(8))) short short8;
typedef __attribute__((ext_vector_type(4))) float f32x4;

__device__ __forceinline__ float b2f(const bf16 v){ return __bfloat162float(v); }

// flag-steered input load: f32 ? fp32 tensor : bf16 tensor
__device__ __forceinline__ float in_ld(const void* p, size_t i, int f32){
  return f32 ? ((const float*)p)[i] : b2f(((const bf16*)p)[i]);
}

__device__ __forceinline__ unsigned int bfbits(float v){
  bf16 b = __float2bfloat16(v);
  return (unsigned int)(*(unsigned short*)&b);
}

// residual load: either fp32 buffer in ws, or native-dtype in d_out
__device__ __forceinline__ float res_ld(const float* residF, const void* dout, int f32, size_t i){
  if (residF) return residF[i];
  return f32 ? ((const float*)dout)[i] : b2f(((const bf16*)dout)[i]);
}
__device__ __forceinline__ float2 res_ld2(const float* residF, const void* dout, int f32, size_t i){
  if (residF) return ((const float2*)residF)[i>>1];
  if (f32)    return ((const float2*)dout)[i>>1];
  unsigned int u = ((const unsigned int*)dout)[i>>1];
  return make_float2(__uint_as_float(u<<16), __uint_as_float(u & 0xFFFF0000u));
}
// 4-channel residual load at channel base 4*li of node n
__device__ __forceinline__ float4 res_ld4(const float* residF, const void* dout, int f32, int n, int li){
  if (residF) return ((const float4*)residF)[(size_t)n*32 + li];
  if (f32)    return ((const float4*)dout)[(size_t)n*32 + li];
  uint2 u = ((const uint2*)dout)[(size_t)n*32 + li];
  float4 r;
  r.x = __uint_as_float(u.x << 16);
  r.y = __uint_as_float(u.x & 0xFFFF0000u);
  r.z = __uint_as_float(u.y << 16);
  r.w = __uint_as_float(u.y & 0xFFFF0000u);
  return r;
}

// ---------------- dtype sniffer ----------------
__global__ void k_sniff(const unsigned int* xb, int* flag){
  int t = threadIdx.x;
  int pl = 0;
  for (int i = t; i < 512; i += 64){
    float v = __uint_as_float(xb[i]);
    float a = fabsf(v);
    if (v == v && a < 1e6f && a > 1e-10f) pl++;
  }
  #pragma unroll
  for (int off = 32; off > 0; off >>= 1) pl += __shfl_down(pl, off);
  if (t == 0) *flag = (pl >= 384) ? 1 : 0;   // >=75% plausible => fp32
}

// ---------------- CSR build ----------------
__global__ __launch_bounds__(256) void k_init(int* __restrict__ deg, int* __restrict__ cursor,
                                              float* __restrict__ gsum, int* __restrict__ gcnt){
  int i = blockIdx.x*256 + threadIdx.x;
  if (i < NN){ deg[i] = 1; cursor[i] = 1; }   // deg=1: self loop (slot 0); cursor starts past it
  if (i < NG*DD) gsum[i] = 0.f;
  if (i < NG) gcnt[i] = 0;
}

__global__ __launch_bounds__(256) void k_hist(const int* __restrict__ dst, int* __restrict__ deg){
  int e = blockIdx.x*256 + threadIdx.x;
  if (e < NE){
    unsigned int d = (unsigned int)dst[e];
    if (d < NN) atomicAdd(&deg[d], 1);
  }
}

__global__ __launch_bounds__(256) void k_scan1(const int* __restrict__ deg, int* __restrict__ incl,
                                               int* __restrict__ bsum){
  __shared__ int tmp[256];
  int t = threadIdx.x, i = blockIdx.x*256 + t;
  int v = (i < NN) ? deg[i] : 0;
  tmp[t] = v; __syncthreads();
  for (int off=1; off<256; off<<=1){
    int a = (t >= off) ? tmp[t-off] : 0;
    __syncthreads();
    tmp[t] += a;
    __syncthreads();
  }
  if (i < NN) incl[i] = tmp[t];
  if (t == 255) bsum[blockIdx.x] = tmp[255];
}

__global__ __launch_bounds__(512) void k_scan2(const int* __restrict__ bsum, int* __restrict__ bex, int nb){
  __shared__ int tmp[512];
  int t = threadIdx.x;
  int v = (t < nb) ? bsum[t] : 0;
  tmp[t] = v; __syncthreads();
  for (int off=1; off<512; off<<=1){
    int a = (t >= off) ? tmp[t-off] : 0;
    __syncthreads();
    tmp[t] += a;
    __syncthreads();
  }
  if (t < nb) bex[t] = tmp[t] - v;  // exclusive block prefix
}

__global__ __launch_bounds__(256) void k_scan3(const int* __restrict__ incl, const int* __restrict__ bex,
                                               int* __restrict__ offs){
  int i = blockIdx.x*256 + threadIdx.x;
  if (i < NN) offs[i+1] = incl[i] + bex[i>>8];
  if (i == 0) offs[0] = 0;
}

// staging base per bucket: offs[b*512] - b*512 (each node has exactly 1 self loop)
__global__ __launch_bounds__(256) void k_binit(const int* __restrict__ offs, int* __restrict__ bcur){
  int b = threadIdx.x + blockIdx.x*256;
  if (b < NBUK){
    int ns = b << BSH;
    bcur[b] = offs[ns] - ns;
  }
}

// Pass 2: bin 4096 edges/block by dst-bucket in LDS, append runs to staging
__global__ __launch_bounds__(256) void k_bin(const int* __restrict__ src, const int* __restrict__ dst,
                                             int* __restrict__ bcur, int2* __restrict__ gstag){
  __shared__ int cnt[NBUK], pref[NBUK+1], place[NBUK], gbase[NBUK];
  __shared__ int2 pairs[4096];   // 32 KB
  int tid = threadIdx.x;
  for (int b = tid; b < NBUK; b += 256){ cnt[b]=0; place[b]=0; }
  __syncthreads();
  int e0 = blockIdx.x*4096;
  int s[16], d[16];
  #pragma unroll
  for (int i=0;i<16;i++){
    int e = e0 + i*256 + tid;
    s[i] = 0; d[i] = -1;
    if (e < NE){
      unsigned int us = (unsigned int)src[e]; if (us >= NN) us = 0;   // firewall
      unsigned int ud = (unsigned int)dst[e]; if (ud >= NN) ud = 0;   // firewall
      s[i] = (int)us; d[i] = (int)ud;
      atomicAdd(&cnt[ud>>BSH], 1);
    }
  }
  __syncthreads();
  if (tid == 0){
    int run = 0;
    for (int b=0;b<NBUK;b++){ pref[b] = run; run += cnt[b]; }
    pref[NBUK] = run;
  }
  __syncthreads();
  for (int b = tid; b < NBUK; b += 256){
    if (cnt[b] > 0) gbase[b] = atomicAdd(&bcur[b], cnt[b]);
  }
  __syncthreads();
  #pragma unroll
  for (int i=0;i<16;i++){
    if (d[i] >= 0){
      int b = d[i]>>BSH;
      int lp = atomicAdd(&place[b],1);
      pairs[pref[b]+lp] = make_int2(s[i], d[i]);
    }
  }
  __syncthreads();
  int tot = pref[NBUK];
  for (int j = tid; j < tot; j += 256){
    int2 pr = pairs[j];
    int b = pr.y>>BSH;
    int gidx = gbase[b] + (j - pref[b]);
    if (gidx >= 0 && gidx < NE) gstag[gidx] = pr;   // firewall
  }
}

// Pass 3: per-bucket CSR segment built in LDS, streamed out coalesced
__global__ __launch_bounds__(256) void k_bucket(const int* __restrict__ offs,
                                                const int2* __restrict__ gstag,
                                                int* __restrict__ csr, int* __restrict__ cursor){
  __shared__ int seg[SEGCAP];   // 37.5 KB
  __shared__ int lcur[512];
  int b = blockIdx.x, tid = threadIdx.x;
  int nstart = b << BSH;
  int nend = min(nstart + 512, NN);
  int nloc = nend - nstart;
  int base = offs[nstart];
  int segN = offs[nend] - base;
  if (segN < 0) segN = 0;
  int ecnt = segN - nloc; if (ecnt < 0) ecnt = 0;
  int estart = base - nstart;          // staging offset of this bucket
  if (segN <= SEGCAP){
    for (int ln = tid; ln < nloc; ln += 256){
      lcur[ln] = 1;
      int p = offs[nstart+ln] - base;
      if (p >= 0 && p < SEGCAP) seg[p] = nstart + ln;     // self loop at slot 0
    }
    __syncthreads();
    for (int j = tid; j < ecnt; j += 256){
      int sidx = estart + j;
      int2 pr = (sidx >= 0 && sidx < NE) ? gstag[sidx] : make_int2(0, nstart);
      int ln = pr.y - nstart;
      if (ln < 0 || ln >= nloc) ln = 0;                   // firewall
      int p = atomicAdd(&lcur[ln], 1);
      int idx = offs[nstart+ln] - base + p;
      if (idx >= 0 && idx < SEGCAP) seg[idx] = pr.x;
    }
    __syncthreads();
    for (int j = tid; j < segN; j += 256) csr[base + j] = seg[j];
  } else {
    // slow path (unreachable for this input): direct global scatter
    for (int ln = tid; ln < nloc; ln += 256){
      int p = offs[nstart+ln];
      if (p >= 0 && p < EP) csr[p] = nstart + ln;
    }
    __syncthreads();
    for (int j = tid; j < ecnt; j += 256){
      int sidx = estart + j;
      int2 pr = (sidx >= 0 && sidx < NE) ? gstag[sidx] : make_int2(0, nstart);
      unsigned int dd = (unsigned int)pr.y; if (dd >= NN) dd = 0;
      int p = atomicAdd(&cursor[dd], 1);
      int idx = offs[dd] + p;
      if (idx >= 0 && idx < EP) csr[idx] = pr.x;
    }
  }
}

// ---------------- W transpose prep (layers 1..3): WT[n][k] = W[k][n], bf16 ----------------
__global__ __launch_bounds__(256) void k_wprep(const void* __restrict__ Ws, bf16* __restrict__ WT,
                                               const int* __restrict__ flag){
  int f32 = *flag;
  int l = blockIdx.x;   // 0..2
  for (int idx = threadIdx.x; idx < DD*DD; idx += 256){
    int n = idx >> 7, k = idx & 127;
    WT[(size_t)l*DD*DD + idx] = __float2bfloat16(in_ld(Ws, (size_t)l*DD*DD + (size_t)k*DD + n, f32));
  }
}

// ---------------- layer-0 projection (IN_DIM=7) + alpha ----------------
__device__ __forceinline__ void alpha_red(float acc, float was, float wad, int d, int n,
                                          float* __restrict__ asrc, float* __restrict__ adst){
  float ps = acc*was, pd = acc*wad;
  #pragma unroll
  for (int off=16; off>0; off>>=1){
    ps += __shfl_down(ps, off, 32);
    pd += __shfl_down(pd, off, 32);
  }
  if ((d & 31) == 0){
    asrc[n*NH + (d>>5)] = ps;
    adst[n*NH + (d>>5)] = pd;
  }
}

__global__ __launch_bounds__(128) void k_gemm0(const void* __restrict__ x, const void* __restrict__ W,
    const void* __restrict__ aws, const void* __restrict__ awd,
    bf16* __restrict__ hproj,
    float* __restrict__ asrc, float* __restrict__ adst, const int* __restrict__ flag){
  int f32 = *flag;
  __shared__ float xr[4][NIN];
  int d = threadIdx.x;
  int n0 = blockIdx.x*4;
  if (d < 4*NIN) xr[d/NIN][d%NIN] = in_ld(x, (size_t)n0*NIN + d, f32);
  __syncthreads();
  float a0=0,a1=0,a2=0,a3=0;
  #pragma unroll
  for (int k=0;k<NIN;k++){
    float w = in_ld(W, (size_t)k*DD + d, f32);
    a0 += xr[0][k]*w; a1 += xr[1][k]*w; a2 += xr[2][k]*w; a3 += xr[3][k]*w;
  }
  hproj[(size_t)(n0+0)*DD+d]=__float2bfloat16(a0);
  hproj[(size_t)(n0+1)*DD+d]=__float2bfloat16(a1);
  hproj[(size_t)(n0+2)*DD+d]=__float2bfloat16(a2);
  hproj[(size_t)(n0+3)*DD+d]=__float2bfloat16(a3);
  float was = in_ld(aws, d, f32), wad = in_ld(awd, d, f32);
  alpha_red(a0, was, wad, d, n0+0, asrc, adst);
  alpha_red(a1, was, wad, d, n0+1, asrc, adst);
  alpha_red(a2, was, wad, d, n0+2, asrc, adst);
  alpha_red(a3, was, wad, d, n0+3, asrc, adst);
}

// ---------------- layers 1..3: MFMA GEMM (64 rows/block) + fused alpha ----------------
// LDS rows padded to 136 elements (272 B): b128 frag reads land 2 lanes/bank (free).
#define LDA 136
#define LDB 136

__global__ __launch_bounds__(256) void k_gemm_mfma(
    const float* __restrict__ residF, const void* __restrict__ dout,
    const bf16* __restrict__ WT, size_t wtoff,
    const void* __restrict__ aws, const void* __restrict__ awd, size_t aoff,
    bf16* __restrict__ hproj,
    float* __restrict__ asrc, float* __restrict__ adst,
    const int* __restrict__ flag)
{
  __shared__ bf16 sA[64*LDA];    // 17.0 KB
  __shared__ bf16 sB[128*LDB];   // 34.0 KB
  int f32 = *flag;
  int t = threadIdx.x;
  int n0 = blockIdx.x*64;

  // stage WT (bf16, [n][k]) -> sB. 128x128 bf16 = 2048 uint4; 16 chunks/row.
  {
    const uint4* srcv = (const uint4*)(WT + wtoff);
    #pragma unroll
    for (int i=0;i<8;i++){
      int u4 = t + 256*i;          // 0..2047
      int row = u4 >> 4, c = u4 & 15;
      *(uint4*)(&sB[row*LDB + c*8]) = srcv[u4];
    }
  }
  // stage A: residual rows n0..n0+63 -> bf16 sA
  {
    #pragma unroll
    for (int i=0;i<16;i++){
      int pidx = t + 256*i;        // pair index 0..4095
      int row = pidx >> 6, colp = pidx & 63;
      int gr = n0 + row;
      float2 v = make_float2(0.f, 0.f);
      if (gr < NN) v = res_ld2(residF, dout, f32, (size_t)gr*DD + colp*2);
      sA[row*LDA + colp*2]     = __float2bfloat16(v.x);
      sA[row*LDA + colp*2 + 1] = __float2bfloat16(v.y);
    }
  }
  __syncthreads();

  int wv = t >> 6, lane = t & 63;
  int m = lane & 15, kq = lane >> 4;      // kq = 0..3
  int rowbase = wv*16;

  f32x4 acc[8];
  #pragma unroll
  for (int nt=0; nt<8; nt++) acc[nt] = (f32x4){0.f,0.f,0.f,0.f};

  #pragma unroll
  for (int ks=0; ks<4; ks++){
    short8 afrag = *(const short8*)(&sA[(rowbase + m)*LDA + ks*32 + kq*8]);
    #pragma unroll
    for (int nt=0; nt<8; nt++){
      short8 bfrag = *(const short8*)(&sB[(nt*16 + m)*LDB + ks*32 + kq*8]);
      acc[nt] = __builtin_amdgcn_mfma_f32_16x16x32_bf16(afrag, bfrag, acc[nt], 0, 0, 0);
    }
  }

  // store C -> hproj (bf16). C/D layout: col = lane&15, row = kq*4 + reg
  #pragma unroll
  for (int reg=0; reg<4; reg++){
    int gr = n0 + rowbase + kq*4 + reg;
    if (gr < NN){
      bf16* dst = hproj + (size_t)gr*DD + m;
      #pragma unroll
      for (int nt=0; nt<8; nt++)
        dst[nt*16] = __float2bfloat16(acc[nt][reg]);
    }
  }

  // fused alpha: per-lane a-vector values at col = nt*16 + m
  float avs[8], avd[8];
  #pragma unroll
  for (int nt=0; nt<8; nt++){
    avs[nt] = in_ld(aws, aoff + nt*16 + m, f32);
    avd[nt] = in_ld(awd, aoff + nt*16 + m, f32);
  }
  #pragma unroll
  for (int h=0; h<4; h++){
    #pragma unroll
    for (int reg=0; reg<4; reg++){
      float ps = acc[2*h][reg]*avs[2*h] + acc[2*h+1][reg]*avs[2*h+1];
      float pd = acc[2*h][reg]*avd[2*h] + acc[2*h+1][reg]*avd[2*h+1];
      #pragma unroll
      for (int off=1; off<16; off<<=1){
        ps += __shfl_xor(ps, off);
        pd += __shfl_xor(pd, off);
      }
      if (m == 0){
        int gr = n0 + rowbase + kq*4 + reg;
        if (gr < NN){
          asrc[gr*NH + h] = ps;
          adst[gr*NH + h] = pd;
        }
      }
    }
  }
}

// ---------------- attention aggregation + LN + ELU + residual ----------------
__device__ __forceinline__ float4 edge_e(const float4 as, const float4 ad){
  float4 l, e;
  l.x = as.x + ad.x; l.y = as.y + ad.y; l.z = as.z + ad.z; l.w = as.w + ad.w;
  l.x = l.x > 0.f ? l.x : 0.2f*l.x;
  l.y = l.y > 0.f ? l.y : 0.2f*l.y;
  l.z = l.z > 0.f ? l.z : 0.2f*l.z;
  l.w = l.w > 0.f ? l.w : 0.2f*l.w;
  l.x = fminf(l.x, 30.f); l.y = fminf(l.y, 30.f);   // firewall: true logits <= ~10
  l.z = fminf(l.z, 30.f); l.w = fminf(l.w, 30.f);
  e.x = __expf(l.x); e.y = __expf(l.y); e.z = __expf(l.z); e.w = __expf(l.w);
  return e;
}

// k_agg lane layout: lane = half*32 + li; lane covers channels 4*li .. 4*li+3.
// Fast path: the two 32-lane halves process edges t and t+1 simultaneously
// (uint2 = 4 bf16 per lane, 256 B per half-wave, fully coalesced).
__global__ __launch_bounds__(256) void k_agg(const bf16* __restrict__ hproj,
    const float* __restrict__ asrc, const float* __restrict__ adst,
    const int* __restrict__ offs, const int* __restrict__ csr,
    float* __restrict__ residF, void* __restrict__ dout,
    const void* __restrict__ bias, size_t boff,
    const void* __restrict__ lng, const void* __restrict__ lnb, size_t lnoff,
    const int* __restrict__ flag, const int first)
{
  __shared__ float s_al[4][256];
  int f32 = *flag;
  int wid = threadIdx.x >> 6, lane = threadIdx.x & 63;
  int half = lane >> 5, li = lane & 31;
  int c0 = li*4;              // channel base for this lane
  int head2 = li >> 3;        // head of channels c0..c0+3 (= c0>>5)
  int n = blockIdx.x*4 + wid; // NN % 4 == 0
  int beg = offs[n];
  int end = offs[n+1];
  beg = max(0, min(beg, EP));
  end = max(beg, min(end, EP));
  int deg = min(end - beg, 1024);    // firewall; true max deg ~50
  const float4 ad = ((const float4*)adst)[n];
  const uint2* hp2 = (const uint2*)hproj;   // row = 32 uint2 (4 bf16 each)
  float4 ac = make_float4(0.f,0.f,0.f,0.f);

  if (deg <= 64){
    float4 e = make_float4(0,0,0,0);
    int sreg = 0;
    if (lane < deg){
      unsigned int us = (unsigned int)csr[beg+lane];
      if (us >= NN) us = 0;          // firewall
      sreg = (int)us;
      float4 as = ((const float4*)asrc)[sreg];
      e = edge_e(as, ad);
    }
    float4 zs = e;
    #pragma unroll
    for (int off=32; off>0; off>>=1){
      zs.x += __shfl_down(zs.x, off);
      zs.y += __shfl_down(zs.y, off);
      zs.z += __shfl_down(zs.z, off);
      zs.w += __shfl_down(zs.w, off);
    }
    float4 invz;
    invz.x = 1.f/(__shfl(zs.x,0)+1e-16f);
    invz.y = 1.f/(__shfl(zs.y,0)+1e-16f);
    invz.z = 1.f/(__shfl(zs.z,0)+1e-16f);
    invz.w = 1.f/(__shfl(zs.w,0)+1e-16f);
    if (lane < deg){
      s_al[wid][lane*4+0] = e.x*invz.x;
      s_al[wid][lane*4+1] = e.y*invz.y;
      s_al[wid][lane*4+2] = e.z*invz.z;
      s_al[wid][lane*4+3] = e.w*invz.w;
    }
    __threadfence_block();
    // halves process edges t+half; x2 unroll = 4 edges, 2 loads in flight
    float4 acb = make_float4(0.f,0.f,0.f,0.f);
    int t = 0;
    for (; t+4 <= deg; t += 4){
      int sA = __shfl(sreg, t + half);
      int sB = __shfl(sreg, t + 2 + half);
      uint2 hA = hp2[(size_t)sA*32 + li];
      uint2 hB = hp2[(size_t)sB*32 + li];
      float aA = s_al[wid][(t+half)*4 + head2];
      float aB = s_al[wid][(t+2+half)*4 + head2];
      ac.x  += __uint_as_float(hA.x << 16)          * aA;
      ac.y  += __uint_as_float(hA.x & 0xFFFF0000u)  * aA;
      ac.z  += __uint_as_float(hA.y << 16)          * aA;
      ac.w  += __uint_as_float(hA.y & 0xFFFF0000u)  * aA;
      acb.x += __uint_as_float(hB.x << 16)          * aB;
      acb.y += __uint_as_float(hB.x & 0xFFFF0000u)  * aB;
      acb.z += __uint_as_float(hB.y << 16)          * aB;
      acb.w += __uint_as_float(hB.y & 0xFFFF0000u)  * aB;
    }
    for (; t+2 <= deg; t += 2){
      int s = __shfl(sreg, t + half);
      uint2 hv = hp2[(size_t)s*32 + li];
      float a = s_al[wid][(t+half)*4 + head2];
      ac.x += __uint_as_float(hv.x << 16)         * a;
      ac.y += __uint_as_float(hv.x & 0xFFFF0000u) * a;
      ac.z += __uint_as_float(hv.y << 16)         * a;
      ac.w += __uint_as_float(hv.y & 0xFFFF0000u) * a;
    }
    if (t < deg){
      int s = __shfl(sreg, t);
      uint2 hv = hp2[(size_t)s*32 + li];
      float a = (half == 0) ? s_al[wid][t*4 + head2] : 0.f;
      ac.x += __uint_as_float(hv.x << 16)         * a;
      ac.y += __uint_as_float(hv.x & 0xFFFF0000u) * a;
      ac.z += __uint_as_float(hv.y << 16)         * a;
      ac.w += __uint_as_float(hv.y & 0xFFFF0000u) * a;
    }
    ac.x += acb.x; ac.y += acb.y; ac.z += acb.z; ac.w += acb.w;
    // combine halves -> both halves hold full sums (duplicated)
    ac.x += __shfl_xor(ac.x, 32);
    ac.y += __shfl_xor(ac.y, 32);
    ac.z += __shfl_xor(ac.z, 32);
    ac.w += __shfl_xor(ac.w, 32);
  } else {
    // general path (cold): both halves duplicate full per-edge work
    float4 zs = make_float4(0,0,0,0);
    for (int j=lane; j<deg; j+=64){
      unsigned int us = (unsigned int)csr[beg+j];
      if (us >= NN) us = 0;
      float4 as = ((const float4*)asrc)[us];
      float4 e = edge_e(as, ad);
      zs.x+=e.x; zs.y+=e.y; zs.z+=e.z; zs.w+=e.w;
    }
    #pragma unroll
    for (int off=32; off>0; off>>=1){
      zs.x += __shfl_down(zs.x, off);
      zs.y += __shfl_down(zs.y, off);
      zs.z += __shfl_down(zs.z, off);
      zs.w += __shfl_down(zs.w, off);
    }
    float4 invz;
    invz.x = 1.f/(__shfl(zs.x,0)+1e-16f);
    invz.y = 1.f/(__shfl(zs.y,0)+1e-16f);
    invz.z = 1.f/(__shfl(zs.z,0)+1e-16f);
    invz.w = 1.f/(__shfl(zs.w,0)+1e-16f);
    int nch = (deg+63)>>6;
    for (int c2=0;c2<nch;c2++){
      int base = c2<<6, j = base+lane;
      int sreg = 0;
      __threadfence_block();
      if (j < deg){
        unsigned int us = (unsigned int)csr[beg+j];
        if (us >= NN) us = 0;
        sreg = (int)us;
        float4 as = ((const float4*)asrc)[sreg];
        float4 e = edge_e(as, ad);
        s_al[wid][lane*4+0]=e.x*invz.x;
        s_al[wid][lane*4+1]=e.y*invz.y;
        s_al[wid][lane*4+2]=e.z*invz.z;
        s_al[wid][lane*4+3]=e.w*invz.w;
      }
      __threadfence_block();
      int cnt = min(64, deg-base);
      for (int tt=0;tt<cnt;tt++){
        int s = __shfl(sreg, tt);
        float a = s_al[wid][tt*4 + head2];
        uint2 hv = hp2[(size_t)s*32 + li];
        ac.x += __uint_as_float(hv.x << 16)         * a;
        ac.y += __uint_as_float(hv.x & 0xFFFF0000u) * a;
        ac.z += __uint_as_float(hv.y << 16)         * a;
        ac.w += __uint_as_float(hv.y & 0xFFFF0000u) * a;
      }
    }
    // no butterfly: each lane already holds full sums for its 4 channels
  }

  // epilogue: bias + layernorm + elu + residual (channels duplicated across halves)
  float4 v;
  v.x = ac.x + in_ld(bias, boff + c0+0, f32);
  v.y = ac.y + in_ld(bias, boff + c0+1, f32);
  v.z = ac.z + in_ld(bias, boff + c0+2, f32);
  v.w = ac.w + in_ld(bias, boff + c0+3, f32);
  float s1 = v.x+v.y+v.z+v.w;
  float s2 = v.x*v.x+v.y*v.y+v.z*v.z+v.w*v.w;
  #pragma unroll
  for (int off=32; off>0; off>>=1){
    s1 += __shfl_down(s1, off);
    s2 += __shfl_down(s2, off);
  }
  // each channel counted twice (both halves)
  float mean = __shfl(s1,0) * (1.f/(2*DD));
  float msq  = __shfl(s2,0) * (1.f/(2*DD));
  float var  = fmaxf(msq - mean*mean, 0.f);
  float r = rsqrtf(var + 1e-5f);
  float4 y;
  y.x = (v.x-mean)*r*in_ld(lng, lnoff+c0+0, f32) + in_ld(lnb, lnoff+c0+0, f32);
  y.y = (v.y-mean)*r*in_ld(lng, lnoff+c0+1, f32) + in_ld(lnb, lnoff+c0+1, f32);
  y.z = (v.z-mean)*r*in_ld(lng, lnoff+c0+2, f32) + in_ld(lnb, lnoff+c0+2, f32);
  y.w = (v.w-mean)*r*in_ld(lng, lnoff+c0+3, f32) + in_ld(lnb, lnoff+c0+3, f32);
  y.x = y.x>0.f ? y.x : expm1f(y.x);
  y.y = y.y>0.f ? y.y : expm1f(y.y);
  y.z = y.z>0.f ? y.z : expm1f(y.z);
  y.w = y.w>0.f ? y.w : expm1f(y.w);
  float4 res;
  if (first){
    res = y;
  } else {
    float4 prev = res_ld4(residF, dout, f32, n, li);
    res = make_float4(prev.x+y.x, prev.y+y.y, prev.z+y.z, prev.w+y.w);
  }
  if (half == 0){
    if (residF){
      ((float4*)residF)[(size_t)n*32 + li] = res;
    } else if (f32){
      ((float4*)dout)[(size_t)n*32 + li] = res;
    } else {
      uint2 pk;
      pk.x = bfbits(res.x) | (bfbits(res.y) << 16);
      pk.y = bfbits(res.z) | (bfbits(res.w) << 16);
      ((uint2*)dout)[(size_t)n*32 + li] = pk;
    }
  }
}

// ---------------- pooling ----------------
__global__ __launch_bounds__(128) void k_pool(const float* __restrict__ residF, void* __restrict__ dout,
    const int* __restrict__ batch, float* __restrict__ gsum, int* __restrict__ gcnt,
    const int* __restrict__ flag){
  __shared__ int sb[64];
  int f32 = *flag;
  int d = threadIdx.x;
  int n0 = blockIdx.x*64;
  int cnt = min(64, NN - n0);
  if (d < cnt){
    unsigned int b = (unsigned int)batch[n0 + d];
    if (b >= NG) b = 0;            // firewall
    sb[d] = (int)b;
  }
  __syncthreads();
  float local = 0.f;
  int cur = sb[0];
  for (int i=0;i<cnt;i++){
    int b = sb[i];
    if (b != cur){
      atomicAdd(&gsum[cur*DD + d], local);
      local = 0.f; cur = b;
    }
    size_t idx = (size_t)(n0+i)*DD + d;
    float v = res_ld(residF, dout, f32, idx);
    if (residF){
      if (f32) ((float*)dout)[idx] = v;
      else     ((bf16*)dout)[idx] = __float2bfloat16(v);
    }
    local += v;
  }
  atomicAdd(&gsum[cur*DD + d], local);
  if (d == 0){
    int lc = 0; int c2 = sb[0];
    for (int i=0;i<cnt;i++){
      int b = sb[i];
      if (b != c2){ atomicAdd(&gcnt[c2], lc); lc = 0; c2 = b; }
      lc++;
    }
    atomicAdd(&gcnt[c2], lc);
  }
}

__global__ __launch_bounds__(128) void k_final(const float* __restrict__ gsum, const int* __restrict__ gcnt,
                                               void* __restrict__ dout, const int* __restrict__ flag){
  int f32 = *flag;
  int i = blockIdx.x*128 + threadIdx.x;
  if (i < NG*DD){
    float c = (float)gcnt[i>>7];
    if (c < 1.f) c = 1.f;
    float val = gsum[i] / c;
    if (f32) ((float*)dout)[(size_t)NN*DD + i] = val;
    else     ((bf16*)dout)[(size_t)NN*DD + i] = __float2bfloat16(val);
  }
}

extern "C" void kernel_launch(void* const* d_in, const int* in_sizes, int n_in,
                              void* d_out, int out_size, void* d_ws, size_t ws_size,
                              hipStream_t stream){
  const void* x      = d_in[0];
  const int*  ei     = (const int*) d_in[1];
  const int*  batch  = (const int*) d_in[2];
  const void* W0     = d_in[3];
  const void* asrc0  = d_in[4];
  const void* adst0  = d_in[5];
  const void* b0     = d_in[6];
  const void* Ws     = d_in[7];
  const void* asrcs  = d_in[8];
  const void* adsts  = d_in[9];
  const void* bs     = d_in[10];
  const void* lng    = d_in[11];
  const void* lnb    = d_in[12];

  const int* srcs = ei;
  const int* dsts = ei + NE;

  uintptr_t p0 = (uintptr_t)d_ws;
  uintptr_t p = p0;
  auto alloc = [&](size_t bytes)->void* {
    void* r = (void*)p; p += (bytes + 255) & ~(size_t)255; return r;
  };
  // fixed pool (~24.7 MB)
  int*   csr    = (int*)  alloc((size_t)EP*4);
  int*   offs   = (int*)  alloc((size_t)(NN+1)*4);
  float* asrc   = (float*)alloc((size_t)NN*NH*4);
  float* adst   = (float*)alloc((size_t)NN*NH*4);
  int*   deg    = (int*)  alloc((size_t)NN*4);
  int*   cursor = (int*)  alloc((size_t)NN*4);
  int*   incl   = (int*)  alloc((size_t)NN*4);
  int*   bsum   = (int*)  alloc(512*4);
  int*   bex    = (int*)  alloc(512*4);
  float* gsum   = (float*)alloc((size_t)NG*DD*4);
  int*   gcnt   = (int*)  alloc(NG*4);
  int*   flag   = (int*)  alloc(256);
  int*   bcur   = (int*)  alloc((size_t)NBUK*4);
  int2*  gstag  = (int2*) alloc((size_t)NE*8);        // 12.8 MB bucketed edge staging
  bf16*  wt     = (bf16*) alloc((size_t)3*DD*DD*2);   // 96 KB, transposed layer weights

  // hproj always bf16 (25.6 MB)
  bf16* hproj = (bf16*)alloc((size_t)NN*DD*2);

  size_t used = (size_t)(p - p0);
  size_t rem  = (ws_size > used) ? (ws_size - used) : 0;
  const size_t RESB = (size_t)NN*DD*4;   // 51.2 MB
  float* residF = nullptr;
  if (rem >= RESB + 4096) residF = (float*)alloc(RESB);   // fp32 residual if it fits

  const int NB = (NN + 255)/256; // 391

  k_sniff<<<1, 64, 0, stream>>>((const unsigned int*)x, flag);
  k_init<<<NB, 256, 0, stream>>>(deg, cursor, gsum, gcnt);
  k_hist<<<(NE+255)/256, 256, 0, stream>>>(dsts, deg);
  k_scan1<<<NB, 256, 0, stream>>>(deg, incl, bsum);
  k_scan2<<<1, 512, 0, stream>>>(bsum, bex, NB);
  k_scan3<<<NB, 256, 0, stream>>>(incl, bex, offs);
  k_binit<<<1, 256, 0, stream>>>(offs, bcur);
  k_bin<<<(NE+4095)/4096, 256, 0, stream>>>(srcs, dsts, bcur, gstag);
  k_bucket<<<NBUK, 256, 0, stream>>>(offs, gstag, csr, cursor);
  k_wprep<<<3, 256, 0, stream>>>(Ws, wt, flag);

  const int GEMM_B = (NN + 63)/64;  // 1563

  for (int l=0; l<4; l++){
    if (l == 0){
      k_gemm0<<<NN/4, 128, 0, stream>>>(x, W0, asrc0, adst0, hproj, asrc, adst, flag);
      k_agg<<<NN/4, 256, 0, stream>>>(hproj, asrc, adst, offs, csr, residF, d_out,
                                      b0, 0, lng, lnb, 0, flag, 1);
    } else {
      size_t wtoff = (size_t)(l-1)*DD*DD;
      size_t aoff  = (size_t)(l-1)*DD;
      k_gemm_mfma<<<GEMM_B, 256, 0, stream>>>(residF, d_out, wt, wtoff,
                                              asrcs, adsts, aoff,
                                              hproj, asrc, adst, flag);
      k_agg<<<NN/4, 256, 0, stream>>>(hproj, asrc, adst, offs, csr, residF, d_out,
                                      bs, (size_t)(l-1)*DD, lng, lnb, (size_t)l*DD, flag, 0);
    }
  }

  k_pool<<<(NN+63)/64, 128, 0, stream>>>(residF, d_out, batch, gsum, gcnt, flag);
  k_final<<<(NG*DD+127)/128, 128, 0, stream>>>(gsum, gcnt, d_out, flag);
}

// Round 10
// 859.340 us; speedup vs baseline: 1.0036x; 1.0036x over previous
//
#include <hip/hip_runtime.h>
#include <hip/hip_bf16.h>

#define NN 100000
#define NE 1600000
#define EP (NE + NN)      // 1700000 edges incl self loops
#define NH 4
#define NC 32
#define DD 128
#define NG 64
#define NIN 7

#define BSH 9                       // bucket = dst >> 9 (512 nodes/bucket)
#define NBUK ((NN + 511) >> BSH)    // 196
#define SEGCAP 9600                 // CSR segment cap (mean 8704, sigma ~90)

typedef __hip_bfloat16 bf16;
typedef __attribute__((ext_vector_type(8))) short short8;
typedef __attribute__((ext_vector_type(4))) float f32x4;

__device__ __forceinline__ float b2f(const bf16 v){ return __bfloat162float(v); }

// flag-steered input load: f32 ? fp32 tensor : bf16 tensor
__device__ __forceinline__ float in_ld(const void* p, size_t i, int f32){
  return f32 ? ((const float*)p)[i] : b2f(((const bf16*)p)[i]);
}

__device__ __forceinline__ unsigned int bfbits(float v){
  bf16 b = __float2bfloat16(v);
  return (unsigned int)(*(unsigned short*)&b);
}

// residual load: either fp32 buffer in ws, or native-dtype in d_out
__device__ __forceinline__ float res_ld(const float* residF, const void* dout, int f32, size_t i){
  if (residF) return residF[i];
  return f32 ? ((const float*)dout)[i] : b2f(((const bf16*)dout)[i]);
}
__device__ __forceinline__ float2 res_ld2(const float* residF, const void* dout, int f32, size_t i){
  if (residF) return ((const float2*)residF)[i>>1];
  if (f32)    return ((const float2*)dout)[i>>1];
  unsigned int u = ((const unsigned int*)dout)[i>>1];
  return make_float2(__uint_as_float(u<<16), __uint_as_float(u & 0xFFFF0000u));
}
// 4-channel residual load at channel base 4*li of node n
__device__ __forceinline__ float4 res_ld4(const float* residF, const void* dout, int f32, int n, int li){
  if (residF) return ((const float4*)residF)[(size_t)n*32 + li];
  if (f32)    return ((const float4*)dout)[(size_t)n*32 + li];
  uint2 u = ((const uint2*)dout)[(size_t)n*32 + li];
  float4 r;
  r.x = __uint_as_float(u.x << 16);
  r.y = __uint_as_float(u.x & 0xFFFF0000u);
  r.z = __uint_as_float(u.y << 16);
  r.w = __uint_as_float(u.y & 0xFFFF0000u);
  return r;
}

// ---------------- dtype sniffer ----------------
__global__ void k_sniff(const unsigned int* xb, int* flag){
  int t = threadIdx.x;
  int pl = 0;
  for (int i = t; i < 512; i += 64){
    float v = __uint_as_float(xb[i]);
    float a = fabsf(v);
    if (v == v && a < 1e6f && a > 1e-10f) pl++;
  }
  #pragma unroll
  for (int off = 32; off > 0; off >>= 1) pl += __shfl_down(pl, off);
  if (t == 0) *flag = (pl >= 384) ? 1 : 0;   // >=75% plausible => fp32
}

// ---------------- CSR build ----------------
__global__ __launch_bounds__(256) void k_init(int* __restrict__ deg, int* __restrict__ cursor,
                                              float* __restrict__ gsum, int* __restrict__ gcnt){
  int i = blockIdx.x*256 + threadIdx.x;
  if (i < NN){ deg[i] = 1; cursor[i] = 1; }   // deg=1: self loop (slot 0); cursor starts past it
  if (i < NG*DD) gsum[i] = 0.f;
  if (i < NG) gcnt[i] = 0;
}

__global__ __launch_bounds__(256) void k_hist(const int* __restrict__ dst, int* __restrict__ deg){
  int e = blockIdx.x*256 + threadIdx.x;
  if (e < NE){
    unsigned int d = (unsigned int)dst[e];
    if (d < NN) atomicAdd(&deg[d], 1);
  }
}

__global__ __launch_bounds__(256) void k_scan1(const int* __restrict__ deg, int* __restrict__ incl,
                                               int* __restrict__ bsum){
  __shared__ int tmp[256];
  int t = threadIdx.x, i = blockIdx.x*256 + t;
  int v = (i < NN) ? deg[i] : 0;
  tmp[t] = v; __syncthreads();
  for (int off=1; off<256; off<<=1){
    int a = (t >= off) ? tmp[t-off] : 0;
    __syncthreads();
    tmp[t] += a;
    __syncthreads();
  }
  if (i < NN) incl[i] = tmp[t];
  if (t == 255) bsum[blockIdx.x] = tmp[255];
}

__global__ __launch_bounds__(512) void k_scan2(const int* __restrict__ bsum, int* __restrict__ bex, int nb){
  __shared__ int tmp[512];
  int t = threadIdx.x;
  int v = (t < nb) ? bsum[t] : 0;
  tmp[t] = v; __syncthreads();
  for (int off=1; off<512; off<<=1){
    int a = (t >= off) ? tmp[t-off] : 0;
    __syncthreads();
    tmp[t] += a;
    __syncthreads();
  }
  if (t < nb) bex[t] = tmp[t] - v;  // exclusive block prefix
}

__global__ __launch_bounds__(256) void k_scan3(const int* __restrict__ incl, const int* __restrict__ bex,
                                               int* __restrict__ offs){
  int i = blockIdx.x*256 + threadIdx.x;
  if (i < NN) offs[i+1] = incl[i] + bex[i>>8];
  if (i == 0) offs[0] = 0;
}

// staging base per bucket: offs[b*512] - b*512 (each node has exactly 1 self loop)
__global__ __launch_bounds__(256) void k_binit(const int* __restrict__ offs, int* __restrict__ bcur){
  int b = threadIdx.x + blockIdx.x*256;
  if (b < NBUK){
    int ns = b << BSH;
    bcur[b] = offs[ns] - ns;
  }
}

// Pass 2: bin 4096 edges/block by dst-bucket in LDS, append runs to staging
__global__ __launch_bounds__(256) void k_bin(const int* __restrict__ src, const int* __restrict__ dst,
                                             int* __restrict__ bcur, int2* __restrict__ gstag){
  __shared__ int cnt[NBUK], pref[NBUK+1], place[NBUK], gbase[NBUK];
  __shared__ int2 pairs[4096];   // 32 KB
  int tid = threadIdx.x;
  for (int b = tid; b < NBUK; b += 256){ cnt[b]=0; place[b]=0; }
  __syncthreads();
  int e0 = blockIdx.x*4096;
  int s[16], d[16];
  #pragma unroll
  for (int i=0;i<16;i++){
    int e = e0 + i*256 + tid;
    s[i] = 0; d[i] = -1;
    if (e < NE){
      unsigned int us = (unsigned int)src[e]; if (us >= NN) us = 0;   // firewall
      unsigned int ud = (unsigned int)dst[e]; if (ud >= NN) ud = 0;   // firewall
      s[i] = (int)us; d[i] = (int)ud;
      atomicAdd(&cnt[ud>>BSH], 1);
    }
  }
  __syncthreads();
  if (tid == 0){
    int run = 0;
    for (int b=0;b<NBUK;b++){ pref[b] = run; run += cnt[b]; }
    pref[NBUK] = run;
  }
  __syncthreads();
  for (int b = tid; b < NBUK; b += 256){
    if (cnt[b] > 0) gbase[b] = atomicAdd(&bcur[b], cnt[b]);
  }
  __syncthreads();
  #pragma unroll
  for (int i=0;i<16;i++){
    if (d[i] >= 0){
      int b = d[i]>>BSH;
      int lp = atomicAdd(&place[b],1);
      pairs[pref[b]+lp] = make_int2(s[i], d[i]);
    }
  }
  __syncthreads();
  int tot = pref[NBUK];
  for (int j = tid; j < tot; j += 256){
    int2 pr = pairs[j];
    int b = pr.y>>BSH;
    int gidx = gbase[b] + (j - pref[b]);
    if (gidx >= 0 && gidx < NE) gstag[gidx] = pr;   // firewall
  }
}

// Pass 3: per-bucket CSR segment built in LDS, streamed out coalesced
__global__ __launch_bounds__(256) void k_bucket(const int* __restrict__ offs,
                                                const int2* __restrict__ gstag,
                                                int* __restrict__ csr, int* __restrict__ cursor){
  __shared__ int seg[SEGCAP];   // 37.5 KB
  __shared__ int lcur[512];
  int b = blockIdx.x, tid = threadIdx.x;
  int nstart = b << BSH;
  int nend = min(nstart + 512, NN);
  int nloc = nend - nstart;
  int base = offs[nstart];
  int segN = offs[nend] - base;
  if (segN < 0) segN = 0;
  int ecnt = segN - nloc; if (ecnt < 0) ecnt = 0;
  int estart = base - nstart;          // staging offset of this bucket
  if (segN <= SEGCAP){
    for (int ln = tid; ln < nloc; ln += 256){
      lcur[ln] = 1;
      int p = offs[nstart+ln] - base;
      if (p >= 0 && p < SEGCAP) seg[p] = nstart + ln;     // self loop at slot 0
    }
    __syncthreads();
    for (int j = tid; j < ecnt; j += 256){
      int sidx = estart + j;
      int2 pr = (sidx >= 0 && sidx < NE) ? gstag[sidx] : make_int2(0, nstart);
      int ln = pr.y - nstart;
      if (ln < 0 || ln >= nloc) ln = 0;                   // firewall
      int p = atomicAdd(&lcur[ln], 1);
      int idx = offs[nstart+ln] - base + p;
      if (idx >= 0 && idx < SEGCAP) seg[idx] = pr.x;
    }
    __syncthreads();
    for (int j = tid; j < segN; j += 256) csr[base + j] = seg[j];
  } else {
    // slow path (unreachable for this input): direct global scatter
    for (int ln = tid; ln < nloc; ln += 256){
      int p = offs[nstart+ln];
      if (p >= 0 && p < EP) csr[p] = nstart + ln;
    }
    __syncthreads();
    for (int j = tid; j < ecnt; j += 256){
      int sidx = estart + j;
      int2 pr = (sidx >= 0 && sidx < NE) ? gstag[sidx] : make_int2(0, nstart);
      unsigned int dd = (unsigned int)pr.y; if (dd >= NN) dd = 0;
      int p = atomicAdd(&cursor[dd], 1);
      int idx = offs[dd] + p;
      if (idx >= 0 && idx < EP) csr[idx] = pr.x;
    }
  }
}

// ---------------- W transpose prep (layers 1..3): WT[n][k] = W[k][n], bf16 ----------------
__global__ __launch_bounds__(256) void k_wprep(const void* __restrict__ Ws, bf16* __restrict__ WT,
                                               const int* __restrict__ flag){
  int f32 = *flag;
  int l = blockIdx.x;   // 0..2
  for (int idx = threadIdx.x; idx < DD*DD; idx += 256){
    int n = idx >> 7, k = idx & 127;
    WT[(size_t)l*DD*DD + idx] = __float2bfloat16(in_ld(Ws, (size_t)l*DD*DD + (size_t)k*DD + n, f32));
  }
}

// ---------------- layer-0 projection (IN_DIM=7) + alpha ----------------
__device__ __forceinline__ void alpha_red(float acc, float was, float wad, int d, int n,
                                          float* __restrict__ asrc, float* __restrict__ adst){
  float ps = acc*was, pd = acc*wad;
  #pragma unroll
  for (int off=16; off>0; off>>=1){
    ps += __shfl_down(ps, off, 32);
    pd += __shfl_down(pd, off, 32);
  }
  if ((d & 31) == 0){
    asrc[n*NH + (d>>5)] = ps;
    adst[n*NH + (d>>5)] = pd;
  }
}

__global__ __launch_bounds__(128) void k_gemm0(const void* __restrict__ x, const void* __restrict__ W,
    const void* __restrict__ aws, const void* __restrict__ awd,
    bf16* __restrict__ hproj,
    float* __restrict__ asrc, float* __restrict__ adst, const int* __restrict__ flag){
  int f32 = *flag;
  __shared__ float xr[4][NIN];
  int d = threadIdx.x;
  int n0 = blockIdx.x*4;
  if (d < 4*NIN) xr[d/NIN][d%NIN] = in_ld(x, (size_t)n0*NIN + d, f32);
  __syncthreads();
  float a0=0,a1=0,a2=0,a3=0;
  #pragma unroll
  for (int k=0;k<NIN;k++){
    float w = in_ld(W, (size_t)k*DD + d, f32);
    a0 += xr[0][k]*w; a1 += xr[1][k]*w; a2 += xr[2][k]*w; a3 += xr[3][k]*w;
  }
  hproj[(size_t)(n0+0)*DD+d]=__float2bfloat16(a0);
  hproj[(size_t)(n0+1)*DD+d]=__float2bfloat16(a1);
  hproj[(size_t)(n0+2)*DD+d]=__float2bfloat16(a2);
  hproj[(size_t)(n0+3)*DD+d]=__float2bfloat16(a3);
  float was = in_ld(aws, d, f32), wad = in_ld(awd, d, f32);
  alpha_red(a0, was, wad, d, n0+0, asrc, adst);
  alpha_red(a1, was, wad, d, n0+1, asrc, adst);
  alpha_red(a2, was, wad, d, n0+2, asrc, adst);
  alpha_red(a3, was, wad, d, n0+3, asrc, adst);
}

// ---------------- layers 1..3: MFMA GEMM (64 rows/block) + fused alpha ----------------
// LDS rows padded to 136 elements (272 B): b128 frag reads land 2 lanes/bank (free).
#define LDA 136
#define LDB 136

__global__ __launch_bounds__(256) void k_gemm_mfma(
    const float* __restrict__ residF, const void* __restrict__ dout,
    const bf16* __restrict__ WT, size_t wtoff,
    const void* __restrict__ aws, const void* __restrict__ awd, size_t aoff,
    bf16* __restrict__ hproj,
    float* __restrict__ asrc, float* __restrict__ adst,
    const int* __restrict__ flag)
{
  __shared__ bf16 sA[64*LDA];    // 17.0 KB
  __shared__ bf16 sB[128*LDB];   // 34.0 KB
  int f32 = *flag;
  int t = threadIdx.x;
  int n0 = blockIdx.x*64;

  // stage WT (bf16, [n][k]) -> sB. 128x128 bf16 = 2048 uint4; 16 chunks/row.
  {
    const uint4* srcv = (const uint4*)(WT + wtoff);
    #pragma unroll
    for (int i=0;i<8;i++){
      int u4 = t + 256*i;          // 0..2047
      int row = u4 >> 4, c = u4 & 15;
      *(uint4*)(&sB[row*LDB + c*8]) = srcv[u4];
    }
  }
  // stage A: residual rows n0..n0+63 -> bf16 sA
  {
    #pragma unroll
    for (int i=0;i<16;i++){
      int pidx = t + 256*i;        // pair index 0..4095
      int row = pidx >> 6, colp = pidx & 63;
      int gr = n0 + row;
      float2 v = make_float2(0.f, 0.f);
      if (gr < NN) v = res_ld2(residF, dout, f32, (size_t)gr*DD + colp*2);
      sA[row*LDA + colp*2]     = __float2bfloat16(v.x);
      sA[row*LDA + colp*2 + 1] = __float2bfloat16(v.y);
    }
  }
  __syncthreads();

  int wv = t >> 6, lane = t & 63;
  int m = lane & 15, kq = lane >> 4;      // kq = 0..3
  int rowbase = wv*16;

  f32x4 acc[8];
  #pragma unroll
  for (int nt=0; nt<8; nt++) acc[nt] = (f32x4){0.f,0.f,0.f,0.f};

  #pragma unroll
  for (int ks=0; ks<4; ks++){
    short8 afrag = *(const short8*)(&sA[(rowbase + m)*LDA + ks*32 + kq*8]);
    #pragma unroll
    for (int nt=0; nt<8; nt++){
      short8 bfrag = *(const short8*)(&sB[(nt*16 + m)*LDB + ks*32 + kq*8]);
      acc[nt] = __builtin_amdgcn_mfma_f32_16x16x32_bf16(afrag, bfrag, acc[nt], 0, 0, 0);
    }
  }

  // store C -> hproj (bf16). C/D layout: col = lane&15, row = kq*4 + reg
  #pragma unroll
  for (int reg=0; reg<4; reg++){
    int gr = n0 + rowbase + kq*4 + reg;
    if (gr < NN){
      bf16* dst = hproj + (size_t)gr*DD + m;
      #pragma unroll
      for (int nt=0; nt<8; nt++)
        dst[nt*16] = __float2bfloat16(acc[nt][reg]);
    }
  }

  // fused alpha: per-lane a-vector values at col = nt*16 + m
  float avs[8], avd[8];
  #pragma unroll
  for (int nt=0; nt<8; nt++){
    avs[nt] = in_ld(aws, aoff + nt*16 + m, f32);
    avd[nt] = in_ld(awd, aoff + nt*16 + m, f32);
  }
  #pragma unroll
  for (int h=0; h<4; h++){
    #pragma unroll
    for (int reg=0; reg<4; reg++){
      float ps = acc[2*h][reg]*avs[2*h] + acc[2*h+1][reg]*avs[2*h+1];
      float pd = acc[2*h][reg]*avd[2*h] + acc[2*h+1][reg]*avd[2*h+1];
      #pragma unroll
      for (int off=1; off<16; off<<=1){
        ps += __shfl_xor(ps, off);
        pd += __shfl_xor(pd, off);
      }
      if (m == 0){
        int gr = n0 + rowbase + kq*4 + reg;
        if (gr < NN){
          asrc[gr*NH + h] = ps;
          adst[gr*NH + h] = pd;
        }
      }
    }
  }
}

// ---------------- attention aggregation + LN + ELU + residual ----------------
__device__ __forceinline__ float4 edge_e(const float4 as, const float4 ad){
  float4 l, e;
  l.x = as.x + ad.x; l.y = as.y + ad.y; l.z = as.z + ad.z; l.w = as.w + ad.w;
  l.x = l.x > 0.f ? l.x : 0.2f*l.x;
  l.y = l.y > 0.f ? l.y : 0.2f*l.y;
  l.z = l.z > 0.f ? l.z : 0.2f*l.z;
  l.w = l.w > 0.f ? l.w : 0.2f*l.w;
  l.x = fminf(l.x, 30.f); l.y = fminf(l.y, 30.f);   // firewall: true logits <= ~10
  l.z = fminf(l.z, 30.f); l.w = fminf(l.w, 30.f);
  e.x = __expf(l.x); e.y = __expf(l.y); e.z = __expf(l.z); e.w = __expf(l.w);
  return e;
}

// k_agg lane layout: lane = half*32 + li; lane covers channels 4*li .. 4*li+3.
// Fast path: halves process edges t and t+1 per load instruction (uint2 = 4 bf16);
// x8-edge unroll keeps 4 independent load instructions in flight.
__global__ __launch_bounds__(256) void k_agg(const bf16* __restrict__ hproj,
    const float* __restrict__ asrc, const float* __restrict__ adst,
    const int* __restrict__ offs, const int* __restrict__ csr,
    float* __restrict__ residF, void* __restrict__ dout,
    const void* __restrict__ bias, size_t boff,
    const void* __restrict__ lng, const void* __restrict__ lnb, size_t lnoff,
    const int* __restrict__ flag, const int first)
{
  __shared__ float s_al[4][256];
  int f32 = *flag;
  int wid = threadIdx.x >> 6, lane = threadIdx.x & 63;
  int half = lane >> 5, li = lane & 31;
  int c0 = li*4;              // channel base for this lane
  int head2 = li >> 3;        // head of channels c0..c0+3 (= c0>>5)
  int n = blockIdx.x*4 + wid; // NN % 4 == 0
  int beg = offs[n];
  int end = offs[n+1];
  beg = max(0, min(beg, EP));
  end = max(beg, min(end, EP));
  int deg = min(end - beg, 1024);    // firewall; true max deg ~50
  const float4 ad = ((const float4*)adst)[n];
  const uint2* hp2 = (const uint2*)hproj;   // row = 32 uint2 (4 bf16 each)
  float4 ac = make_float4(0.f,0.f,0.f,0.f);

  if (deg <= 64){
    float4 e = make_float4(0,0,0,0);
    int sreg = 0;
    if (lane < deg){
      unsigned int us = (unsigned int)csr[beg+lane];
      if (us >= NN) us = 0;          // firewall
      sreg = (int)us;
      float4 as = ((const float4*)asrc)[sreg];
      e = edge_e(as, ad);
    }
    float4 zs = e;
    #pragma unroll
    for (int off=32; off>0; off>>=1){
      zs.x += __shfl_down(zs.x, off);
      zs.y += __shfl_down(zs.y, off);
      zs.z += __shfl_down(zs.z, off);
      zs.w += __shfl_down(zs.w, off);
    }
    float4 invz;
    invz.x = 1.f/(__shfl(zs.x,0)+1e-16f);
    invz.y = 1.f/(__shfl(zs.y,0)+1e-16f);
    invz.z = 1.f/(__shfl(zs.z,0)+1e-16f);
    invz.w = 1.f/(__shfl(zs.w,0)+1e-16f);
    if (lane < deg){
      s_al[wid][lane*4+0] = e.x*invz.x;
      s_al[wid][lane*4+1] = e.y*invz.y;
      s_al[wid][lane*4+2] = e.z*invz.z;
      s_al[wid][lane*4+3] = e.w*invz.w;
    }
    __threadfence_block();
    // x8-edge unroll: 4 independent uint2 load instructions in flight
    float4 ac1 = make_float4(0.f,0.f,0.f,0.f);
    float4 ac2 = make_float4(0.f,0.f,0.f,0.f);
    float4 ac3 = make_float4(0.f,0.f,0.f,0.f);
    int t = 0;
    for (; t+8 <= deg; t += 8){
      int sA = __shfl(sreg, t     + half);
      int sB = __shfl(sreg, t + 2 + half);
      int sC = __shfl(sreg, t + 4 + half);
      int sD = __shfl(sreg, t + 6 + half);
      uint2 hA = hp2[(size_t)sA*32 + li];
      uint2 hB = hp2[(size_t)sB*32 + li];
      uint2 hC = hp2[(size_t)sC*32 + li];
      uint2 hD = hp2[(size_t)sD*32 + li];
      float aA = s_al[wid][(t  +half)*4 + head2];
      float aB = s_al[wid][(t+2+half)*4 + head2];
      float aC = s_al[wid][(t+4+half)*4 + head2];
      float aD = s_al[wid][(t+6+half)*4 + head2];
      ac.x  += __uint_as_float(hA.x << 16)          * aA;
      ac.y  += __uint_as_float(hA.x & 0xFFFF0000u)  * aA;
      ac.z  += __uint_as_float(hA.y << 16)          * aA;
      ac.w  += __uint_as_float(hA.y & 0xFFFF0000u)  * aA;
      ac1.x += __uint_as_float(hB.x << 16)          * aB;
      ac1.y += __uint_as_float(hB.x & 0xFFFF0000u)  * aB;
      ac1.z += __uint_as_float(hB.y << 16)          * aB;
      ac1.w += __uint_as_float(hB.y & 0xFFFF0000u)  * aB;
      ac2.x += __uint_as_float(hC.x << 16)          * aC;
      ac2.y += __uint_as_float(hC.x & 0xFFFF0000u)  * aC;
      ac2.z += __uint_as_float(hC.y << 16)          * aC;
      ac2.w += __uint_as_float(hC.y & 0xFFFF0000u)  * aC;
      ac3.x += __uint_as_float(hD.x << 16)          * aD;
      ac3.y += __uint_as_float(hD.x & 0xFFFF0000u)  * aD;
      ac3.z += __uint_as_float(hD.y << 16)          * aD;
      ac3.w += __uint_as_float(hD.y & 0xFFFF0000u)  * aD;
    }
    for (; t+2 <= deg; t += 2){
      int s = __shfl(sreg, t + half);
      uint2 hv = hp2[(size_t)s*32 + li];
      float a = s_al[wid][(t+half)*4 + head2];
      ac.x += __uint_as_float(hv.x << 16)         * a;
      ac.y += __uint_as_float(hv.x & 0xFFFF0000u) * a;
      ac.z += __uint_as_float(hv.y << 16)         * a;
      ac.w += __uint_as_float(hv.y & 0xFFFF0000u) * a;
    }
    if (t < deg){
      int s = __shfl(sreg, t);
      uint2 hv = hp2[(size_t)s*32 + li];
      float a = (half == 0) ? s_al[wid][t*4 + head2] : 0.f;
      ac.x += __uint_as_float(hv.x << 16)         * a;
      ac.y += __uint_as_float(hv.x & 0xFFFF0000u) * a;
      ac.z += __uint_as_float(hv.y << 16)         * a;
      ac.w += __uint_as_float(hv.y & 0xFFFF0000u) * a;
    }
    ac.x += ac1.x + ac2.x + ac3.x;
    ac.y += ac1.y + ac2.y + ac3.y;
    ac.z += ac1.z + ac2.z + ac3.z;
    ac.w += ac1.w + ac2.w + ac3.w;
    // combine halves -> both halves hold full sums (duplicated)
    ac.x += __shfl_xor(ac.x, 32);
    ac.y += __shfl_xor(ac.y, 32);
    ac.z += __shfl_xor(ac.z, 32);
    ac.w += __shfl_xor(ac.w, 32);
  } else {
    // general path (cold): both halves duplicate full per-edge work
    float4 zs = make_float4(0,0,0,0);
    for (int j=lane; j<deg; j+=64){
      unsigned int us = (unsigned int)csr[beg+j];
      if (us >= NN) us = 0;
      float4 as = ((const float4*)asrc)[us];
      float4 e = edge_e(as, ad);
      zs.x+=e.x; zs.y+=e.y; zs.z+=e.z; zs.w+=e.w;
    }
    #pragma unroll
    for (int off=32; off>0; off>>=1){
      zs.x += __shfl_down(zs.x, off);
      zs.y += __shfl_down(zs.y, off);
      zs.z += __shfl_down(zs.z, off);
      zs.w += __shfl_down(zs.w, off);
    }
    float4 invz;
    invz.x = 1.f/(__shfl(zs.x,0)+1e-16f);
    invz.y = 1.f/(__shfl(zs.y,0)+1e-16f);
    invz.z = 1.f/(__shfl(zs.z,0)+1e-16f);
    invz.w = 1.f/(__shfl(zs.w,0)+1e-16f);
    int nch = (deg+63)>>6;
    for (int c2=0;c2<nch;c2++){
      int base = c2<<6, j = base+lane;
      int sreg = 0;
      __threadfence_block();
      if (j < deg){
        unsigned int us = (unsigned int)csr[beg+j];
        if (us >= NN) us = 0;
        sreg = (int)us;
        float4 as = ((const float4*)asrc)[sreg];
        float4 e = edge_e(as, ad);
        s_al[wid][lane*4+0]=e.x*invz.x;
        s_al[wid][lane*4+1]=e.y*invz.y;
        s_al[wid][lane*4+2]=e.z*invz.z;
        s_al[wid][lane*4+3]=e.w*invz.w;
      }
      __threadfence_block();
      int cnt = min(64, deg-base);
      for (int tt=0;tt<cnt;tt++){
        int s = __shfl(sreg, tt);
        float a = s_al[wid][tt*4 + head2];
        uint2 hv = hp2[(size_t)s*32 + li];
        ac.x += __uint_as_float(hv.x << 16)         * a;
        ac.y += __uint_as_float(hv.x & 0xFFFF0000u) * a;
        ac.z += __uint_as_float(hv.y << 16)         * a;
        ac.w += __uint_as_float(hv.y & 0xFFFF0000u) * a;
      }
    }
    // no butterfly: each lane already holds full sums for its 4 channels
  }

  // epilogue: bias + layernorm + elu + residual (channels duplicated across halves)
  float4 v;
  v.x = ac.x + in_ld(bias, boff + c0+0, f32);
  v.y = ac.y + in_ld(bias, boff + c0+1, f32);
  v.z = ac.z + in_ld(bias, boff + c0+2, f32);
  v.w = ac.w + in_ld(bias, boff + c0+3, f32);
  float s1 = v.x+v.y+v.z+v.w;
  float s2 = v.x*v.x+v.y*v.y+v.z*v.z+v.w*v.w;
  #pragma unroll
  for (int off=32; off>0; off>>=1){
    s1 += __shfl_down(s1, off);
    s2 += __shfl_down(s2, off);
  }
  // each channel counted twice (both halves)
  float mean = __shfl(s1,0) * (1.f/(2*DD));
  float msq  = __shfl(s2,0) * (1.f/(2*DD));
  float var  = fmaxf(msq - mean*mean, 0.f);
  float r = rsqrtf(var + 1e-5f);
  float4 y;
  y.x = (v.x-mean)*r*in_ld(lng, lnoff+c0+0, f32) + in_ld(lnb, lnoff+c0+0, f32);
  y.y = (v.y-mean)*r*in_ld(lng, lnoff+c0+1, f32) + in_ld(lnb, lnoff+c0+1, f32);
  y.z = (v.z-mean)*r*in_ld(lng, lnoff+c0+2, f32) + in_ld(lnb, lnoff+c0+2, f32);
  y.w = (v.w-mean)*r*in_ld(lng, lnoff+c0+3, f32) + in_ld(lnb, lnoff+c0+3, f32);
  y.x = y.x>0.f ? y.x : expm1f(y.x);
  y.y = y.y>0.f ? y.y : expm1f(y.y);
  y.z = y.z>0.f ? y.z : expm1f(y.z);
  y.w = y.w>0.f ? y.w : expm1f(y.w);
  float4 res;
  if (first){
    res = y;
  } else {
    float4 prev = res_ld4(residF, dout, f32, n, li);
    res = make_float4(prev.x+y.x, prev.y+y.y, prev.z+y.z, prev.w+y.w);
  }
  if (half == 0){
    if (residF){
      ((float4*)residF)[(size_t)n*32 + li] = res;
    } else if (f32){
      ((float4*)dout)[(size_t)n*32 + li] = res;
    } else {
      uint2 pk;
      pk.x = bfbits(res.x) | (bfbits(res.y) << 16);
      pk.y = bfbits(res.z) | (bfbits(res.w) << 16);
      ((uint2*)dout)[(size_t)n*32 + li] = pk;
    }
  }
}

// ---------------- pooling ----------------
__global__ __launch_bounds__(128) void k_pool(const float* __restrict__ residF, void* __restrict__ dout,
    const int* __restrict__ batch, float* __restrict__ gsum, int* __restrict__ gcnt,
    const int* __restrict__ flag){
  __shared__ int sb[64];
  int f32 = *flag;
  int d = threadIdx.x;
  int n0 = blockIdx.x*64;
  int cnt = min(64, NN - n0);
  if (d < cnt){
    unsigned int b = (unsigned int)batch[n0 + d];
    if (b >= NG) b = 0;            // firewall
    sb[d] = (int)b;
  }
  __syncthreads();
  float local = 0.f;
  int cur = sb[0];
  for (int i=0;i<cnt;i++){
    int b = sb[i];
    if (b != cur){
      atomicAdd(&gsum[cur*DD + d], local);
      local = 0.f; cur = b;
    }
    size_t idx = (size_t)(n0+i)*DD + d;
    float v = res_ld(residF, dout, f32, idx);
    if (residF){
      if (f32) ((float*)dout)[idx] = v;
      else     ((bf16*)dout)[idx] = __float2bfloat16(v);
    }
    local += v;
  }
  atomicAdd(&gsum[cur*DD + d], local);
  if (d == 0){
    int lc = 0; int c2 = sb[0];
    for (int i=0;i<cnt;i++){
      int b = sb[i];
      if (b != c2){ atomicAdd(&gcnt[c2], lc); lc = 0; c2 = b; }
      lc++;
    }
    atomicAdd(&gcnt[c2], lc);
  }
}

__global__ __launch_bounds__(128) void k_final(const float* __restrict__ gsum, const int* __restrict__ gcnt,
                                               void* __restrict__ dout, const int* __restrict__ flag){
  int f32 = *flag;
  int i = blockIdx.x*128 + threadIdx.x;
  if (i < NG*DD){
    float c = (float)gcnt[i>>7];
    if (c < 1.f) c = 1.f;
    float val = gsum[i] / c;
    if (f32) ((float*)dout)[(size_t)NN*DD + i] = val;
    else     ((bf16*)dout)[(size_t)NN*DD + i] = __float2bfloat16(val);
  }
}

extern "C" void kernel_launch(void* const* d_in, const int* in_sizes, int n_in,
                              void* d_out, int out_size, void* d_ws, size_t ws_size,
                              hipStream_t stream){
  const void* x      = d_in[0];
  const int*  ei     = (const int*) d_in[1];
  const int*  batch  = (const int*) d_in[2];
  const void* W0     = d_in[3];
  const void* asrc0  = d_in[4];
  const void* adst0  = d_in[5];
  const void* b0     = d_in[6];
  const void* Ws     = d_in[7];
  const void* asrcs  = d_in[8];
  const void* adsts  = d_in[9];
  const void* bs     = d_in[10];
  const void* lng    = d_in[11];
  const void* lnb    = d_in[12];

  const int* srcs = ei;
  const int* dsts = ei + NE;

  uintptr_t p0 = (uintptr_t)d_ws;
  uintptr_t p = p0;
  auto alloc = [&](size_t bytes)->void* {
    void* r = (void*)p; p += (bytes + 255) & ~(size_t)255; return r;
  };
  // fixed pool (~24.7 MB)
  int*   csr    = (int*)  alloc((size_t)EP*4);
  int*   offs   = (int*)  alloc((size_t)(NN+1)*4);
  float* asrc   = (float*)alloc((size_t)NN*NH*4);
  float* adst   = (float*)alloc((size_t)NN*NH*4);
  int*   deg    = (int*)  alloc((size_t)NN*4);
  int*   cursor = (int*)  alloc((size_t)NN*4);
  int*   incl   = (int*)  alloc((size_t)NN*4);
  int*   bsum   = (int*)  alloc(512*4);
  int*   bex    = (int*)  alloc(512*4);
  float* gsum   = (float*)alloc((size_t)NG*DD*4);
  int*   gcnt   = (int*)  alloc(NG*4);
  int*   flag   = (int*)  alloc(256);
  int*   bcur   = (int*)  alloc((size_t)NBUK*4);
  int2*  gstag  = (int2*) alloc((size_t)NE*8);        // 12.8 MB bucketed edge staging
  bf16*  wt     = (bf16*) alloc((size_t)3*DD*DD*2);   // 96 KB, transposed layer weights

  // hproj always bf16 (25.6 MB)
  bf16* hproj = (bf16*)alloc((size_t)NN*DD*2);

  size_t used = (size_t)(p - p0);
  size_t rem  = (ws_size > used) ? (ws_size - used) : 0;
  const size_t RESB = (size_t)NN*DD*4;   // 51.2 MB
  float* residF = nullptr;
  if (rem >= RESB + 4096) residF = (float*)alloc(RESB);   // fp32 residual if it fits

  const int NB = (NN + 255)/256; // 391

  k_sniff<<<1, 64, 0, stream>>>((const unsigned int*)x, flag);
  k_init<<<NB, 256, 0, stream>>>(deg, cursor, gsum, gcnt);
  k_hist<<<(NE+255)/256, 256, 0, stream>>>(dsts, deg);
  k_scan1<<<NB, 256, 0, stream>>>(deg, incl, bsum);
  k_scan2<<<1, 512, 0, stream>>>(bsum, bex, NB);
  k_scan3<<<NB, 256, 0, stream>>>(incl, bex, offs);
  k_binit<<<1, 256, 0, stream>>>(offs, bcur);
  k_bin<<<(NE+4095)/4096, 256, 0, stream>>>(srcs, dsts, bcur, gstag);
  k_bucket<<<NBUK, 256, 0, stream>>>(offs, gstag, csr, cursor);
  k_wprep<<<3, 256, 0, stream>>>(Ws, wt, flag);

  const int GEMM_B = (NN + 63)/64;  // 1563

  for (int l=0; l<4; l++){
    if (l == 0){
      k_gemm0<<<NN/4, 128, 0, stream>>>(x, W0, asrc0, adst0, hproj, asrc, adst, flag);
      k_agg<<<NN/4, 256, 0, stream>>>(hproj, asrc, adst, offs, csr, residF, d_out,
                                      b0, 0, lng, lnb, 0, flag, 1);
    } else {
      size_t wtoff = (size_t)(l-1)*DD*DD;
      size_t aoff  = (size_t)(l-1)*DD;
      k_gemm_mfma<<<GEMM_B, 256, 0, stream>>>(residF, d_out, wt, wtoff,
                                              asrcs, adsts, aoff,
                                              hproj, asrc, adst, flag);
      k_agg<<<NN/4, 256, 0, stream>>>(hproj, asrc, adst, offs, csr, residF, d_out,
                                      bs, (size_t)(l-1)*DD, lng, lnb, (size_t)l*DD, flag, 0);
    }
  }

  k_pool<<<(NN+63)/64, 128, 0, stream>>>(residF, d_out, batch, gsum, gcnt, flag);
  k_final<<<(NG*DD+127)/128, 128, 0, stream>>>(gsum, gcnt, d_out, flag);
}

// Round 11
// 762.449 us; speedup vs baseline: 1.1312x; 1.1271x over previous
//
#include <hip/hip_runtime.h>
#include <hip/hip_bf16.h>

#define NN 100000
#define NE 1600000
#define EP (NE + NN)      // 1700000 edges incl self loops
#define NH 4
#define NC 32
#define DD 128
#define NG 64
#define NIN 7

#define BSH 9                       // bucket = dst >> 9 (512 nodes/bucket)
#define NBUK ((NN + 511) >> BSH)    // 196
#define SEGCAP 9600                 // CSR segment cap (mean 8704, sigma ~90)
#define NHB ((NE + 255)/256)        // 6250 hist blocks

typedef __hip_bfloat16 bf16;
typedef __attribute__((ext_vector_type(8))) short short8;
typedef __attribute__((ext_vector_type(4))) float f32x4;

__device__ __forceinline__ float b2f(const bf16 v){ return __bfloat162float(v); }

// flag-steered input load: f32 ? fp32 tensor : bf16 tensor
__device__ __forceinline__ float in_ld(const void* p, size_t i, int f32){
  return f32 ? ((const float*)p)[i] : b2f(((const bf16*)p)[i]);
}

// residual load: either fp32 buffer in ws, or native-dtype in d_out
__device__ __forceinline__ float res_ld(const float* residF, const void* dout, int f32, size_t i){
  if (residF) return residF[i];
  return f32 ? ((const float*)dout)[i] : b2f(((const bf16*)dout)[i]);
}
__device__ __forceinline__ float2 res_ld2(const float* residF, const void* dout, int f32, size_t i){
  if (residF) return ((const float2*)residF)[i>>1];
  if (f32)    return ((const float2*)dout)[i>>1];
  unsigned int u = ((const unsigned int*)dout)[i>>1];
  return make_float2(__uint_as_float(u<<16), __uint_as_float(u & 0xFFFF0000u));
}

// ---------------- init (+ dtype sniffer in block 0) ----------------
__global__ __launch_bounds__(256) void k_init(int* __restrict__ deg, int* __restrict__ cursor,
                                              float* __restrict__ gsum, int* __restrict__ gcnt,
                                              const unsigned int* __restrict__ xb, int* __restrict__ flag){
  int i = blockIdx.x*256 + threadIdx.x;
  if (i < NN){ deg[i] = 1; cursor[i] = 1; }   // deg=1: self loop (slot 0); cursor starts past it
  if (i < NG*DD) gsum[i] = 0.f;
  if (i < NG) gcnt[i] = 0;
  if (blockIdx.x == 0 && threadIdx.x < 64){
    int t = threadIdx.x;
    int pl = 0;
    for (int j = t; j < 512; j += 64){
      float v = __uint_as_float(xb[j]);
      float a = fabsf(v);
      if (v == v && a < 1e6f && a > 1e-10f) pl++;
    }
    #pragma unroll
    for (int off = 32; off > 0; off >>= 1) pl += __shfl_down(pl, off);
    if (t == 0) *flag = (pl >= 384) ? 1 : 0;   // >=75% plausible => fp32
  }
}

// ---------------- CSR build (+ W-transpose prep in tail blocks) ----------------
__global__ __launch_bounds__(256) void k_hist(const int* __restrict__ dst, int* __restrict__ deg,
                                              const void* __restrict__ Ws, bf16* __restrict__ WT,
                                              const int* __restrict__ flag){
  if (blockIdx.x >= NHB){
    // WT[n][k] = W[k][n], bf16 — 3 layers, one block each
    int l = blockIdx.x - NHB;   // 0..2
    int f32 = *flag;            // written by k_init (prior launch, stream-ordered)
    for (int idx = threadIdx.x; idx < DD*DD; idx += 256){
      int n = idx >> 7, k = idx & 127;
      WT[(size_t)l*DD*DD + idx] = __float2bfloat16(in_ld(Ws, (size_t)l*DD*DD + (size_t)k*DD + n, f32));
    }
    return;
  }
  int e = blockIdx.x*256 + threadIdx.x;
  if (e < NE){
    unsigned int d = (unsigned int)dst[e];
    if (d < NN) atomicAdd(&deg[d], 1);
  }
}

__global__ __launch_bounds__(256) void k_scan1(const int* __restrict__ deg, int* __restrict__ incl,
                                               int* __restrict__ bsum){
  __shared__ int tmp[256];
  int t = threadIdx.x, i = blockIdx.x*256 + t;
  int v = (i < NN) ? deg[i] : 0;
  tmp[t] = v; __syncthreads();
  for (int off=1; off<256; off<<=1){
    int a = (t >= off) ? tmp[t-off] : 0;
    __syncthreads();
    tmp[t] += a;
    __syncthreads();
  }
  if (i < NN) incl[i] = tmp[t];
  if (t == 255) bsum[blockIdx.x] = tmp[255];
}

__global__ __launch_bounds__(512) void k_scan2(const int* __restrict__ bsum, int* __restrict__ bex, int nb){
  __shared__ int tmp[512];
  int t = threadIdx.x;
  int v = (t < nb) ? bsum[t] : 0;
  tmp[t] = v; __syncthreads();
  for (int off=1; off<512; off<<=1){
    int a = (t >= off) ? tmp[t-off] : 0;
    __syncthreads();
    tmp[t] += a;
    __syncthreads();
  }
  if (t < nb) bex[t] = tmp[t] - v;  // exclusive block prefix
}

__global__ __launch_bounds__(256) void k_scan3(const int* __restrict__ incl, const int* __restrict__ bex,
                                               int* __restrict__ offs){
  int i = blockIdx.x*256 + threadIdx.x;
  if (i < NN) offs[i+1] = incl[i] + bex[i>>8];
  if (i == 0) offs[0] = 0;
}

// staging base per bucket: offs[b*512] - b*512 (each node has exactly 1 self loop)
__global__ __launch_bounds__(256) void k_binit(const int* __restrict__ offs, int* __restrict__ bcur){
  int b = threadIdx.x + blockIdx.x*256;
  if (b < NBUK){
    int ns = b << BSH;
    bcur[b] = offs[ns] - ns;
  }
}

// Pass 2: bin 4096 edges/block by dst-bucket in LDS, append runs to staging
__global__ __launch_bounds__(256) void k_bin(const int* __restrict__ src, const int* __restrict__ dst,
                                             int* __restrict__ bcur, int2* __restrict__ gstag){
  __shared__ int cnt[NBUK], pref[NBUK+1], place[NBUK], gbase[NBUK];
  __shared__ int2 pairs[4096];   // 32 KB
  int tid = threadIdx.x;
  for (int b = tid; b < NBUK; b += 256){ cnt[b]=0; place[b]=0; }
  __syncthreads();
  int e0 = blockIdx.x*4096;
  int s[16], d[16];
  #pragma unroll
  for (int i=0;i<16;i++){
    int e = e0 + i*256 + tid;
    s[i] = 0; d[i] = -1;
    if (e < NE){
      unsigned int us = (unsigned int)src[e]; if (us >= NN) us = 0;   // firewall
      unsigned int ud = (unsigned int)dst[e]; if (ud >= NN) ud = 0;   // firewall
      s[i] = (int)us; d[i] = (int)ud;
      atomicAdd(&cnt[ud>>BSH], 1);
    }
  }
  __syncthreads();
  if (tid == 0){
    int run = 0;
    for (int b=0;b<NBUK;b++){ pref[b] = run; run += cnt[b]; }
    pref[NBUK] = run;
  }
  __syncthreads();
  for (int b = tid; b < NBUK; b += 256){
    if (cnt[b] > 0) gbase[b] = atomicAdd(&bcur[b], cnt[b]);
  }
  __syncthreads();
  #pragma unroll
  for (int i=0;i<16;i++){
    if (d[i] >= 0){
      int b = d[i]>>BSH;
      int lp = atomicAdd(&place[b],1);
      pairs[pref[b]+lp] = make_int2(s[i], d[i]);
    }
  }
  __syncthreads();
  int tot = pref[NBUK];
  for (int j = tid; j < tot; j += 256){
    int2 pr = pairs[j];
    int b = pr.y>>BSH;
    int gidx = gbase[b] + (j - pref[b]);
    if (gidx >= 0 && gidx < NE) gstag[gidx] = pr;   // firewall
  }
}

// Pass 3: per-bucket CSR segment built in LDS, streamed out coalesced
__global__ __launch_bounds__(256) void k_bucket(const int* __restrict__ offs,
                                                const int2* __restrict__ gstag,
                                                int* __restrict__ csr, int* __restrict__ cursor){
  __shared__ int seg[SEGCAP];   // 37.5 KB
  __shared__ int lcur[512];
  int b = blockIdx.x, tid = threadIdx.x;
  int nstart = b << BSH;
  int nend = min(nstart + 512, NN);
  int nloc = nend - nstart;
  int base = offs[nstart];
  int segN = offs[nend] - base;
  if (segN < 0) segN = 0;
  int ecnt = segN - nloc; if (ecnt < 0) ecnt = 0;
  int estart = base - nstart;          // staging offset of this bucket
  if (segN <= SEGCAP){
    for (int ln = tid; ln < nloc; ln += 256){
      lcur[ln] = 1;
      int p = offs[nstart+ln] - base;
      if (p >= 0 && p < SEGCAP) seg[p] = nstart + ln;     // self loop at slot 0
    }
    __syncthreads();
    for (int j = tid; j < ecnt; j += 256){
      int sidx = estart + j;
      int2 pr = (sidx >= 0 && sidx < NE) ? gstag[sidx] : make_int2(0, nstart);
      int ln = pr.y - nstart;
      if (ln < 0 || ln >= nloc) ln = 0;                   // firewall
      int p = atomicAdd(&lcur[ln], 1);
      int idx = offs[nstart+ln] - base + p;
      if (idx >= 0 && idx < SEGCAP) seg[idx] = pr.x;
    }
    __syncthreads();
    for (int j = tid; j < segN; j += 256) csr[base + j] = seg[j];
  } else {
    // slow path (unreachable for this input): direct global scatter
    for (int ln = tid; ln < nloc; ln += 256){
      int p = offs[nstart+ln];
      if (p >= 0 && p < EP) csr[p] = nstart + ln;
    }
    __syncthreads();
    for (int j = tid; j < ecnt; j += 256){
      int sidx = estart + j;
      int2 pr = (sidx >= 0 && sidx < NE) ? gstag[sidx] : make_int2(0, nstart);
      unsigned int dd = (unsigned int)pr.y; if (dd >= NN) dd = 0;
      int p = atomicAdd(&cursor[dd], 1);
      int idx = offs[dd] + p;
      if (idx >= 0 && idx < EP) csr[idx] = pr.x;
    }
  }
}

// ---------------- layer-0 projection (IN_DIM=7) + alpha ----------------
__device__ __forceinline__ void alpha_red(float acc, float was, float wad, int d, int n,
                                          float* __restrict__ asrc, float* __restrict__ adst){
  float ps = acc*was, pd = acc*wad;
  #pragma unroll
  for (int off=16; off>0; off>>=1){
    ps += __shfl_down(ps, off, 32);
    pd += __shfl_down(pd, off, 32);
  }
  if ((d & 31) == 0){
    asrc[n*NH + (d>>5)] = ps;
    adst[n*NH + (d>>5)] = pd;
  }
}

__global__ __launch_bounds__(128) void k_gemm0(const void* __restrict__ x, const void* __restrict__ W,
    const void* __restrict__ aws, const void* __restrict__ awd,
    bf16* __restrict__ hproj,
    float* __restrict__ asrc, float* __restrict__ adst, const int* __restrict__ flag){
  int f32 = *flag;
  __shared__ float xr[4][NIN];
  int d = threadIdx.x;
  int n0 = blockIdx.x*4;
  if (d < 4*NIN) xr[d/NIN][d%NIN] = in_ld(x, (size_t)n0*NIN + d, f32);
  __syncthreads();
  float a0=0,a1=0,a2=0,a3=0;
  #pragma unroll
  for (int k=0;k<NIN;k++){
    float w = in_ld(W, (size_t)k*DD + d, f32);
    a0 += xr[0][k]*w; a1 += xr[1][k]*w; a2 += xr[2][k]*w; a3 += xr[3][k]*w;
  }
  hproj[(size_t)(n0+0)*DD+d]=__float2bfloat16(a0);
  hproj[(size_t)(n0+1)*DD+d]=__float2bfloat16(a1);
  hproj[(size_t)(n0+2)*DD+d]=__float2bfloat16(a2);
  hproj[(size_t)(n0+3)*DD+d]=__float2bfloat16(a3);
  float was = in_ld(aws, d, f32), wad = in_ld(awd, d, f32);
  alpha_red(a0, was, wad, d, n0+0, asrc, adst);
  alpha_red(a1, was, wad, d, n0+1, asrc, adst);
  alpha_red(a2, was, wad, d, n0+2, asrc, adst);
  alpha_red(a3, was, wad, d, n0+3, asrc, adst);
}

// ---------------- layers 1..3: MFMA GEMM (64 rows/block) + fused alpha ----------------
// LDS rows padded to 136 elements (272 B): b128 frag reads land 2 lanes/bank (free).
#define LDA 136
#define LDB 136

__global__ __launch_bounds__(256) void k_gemm_mfma(
    const float* __restrict__ residF, const void* __restrict__ dout,
    const bf16* __restrict__ WT, size_t wtoff,
    const void* __restrict__ aws, const void* __restrict__ awd, size_t aoff,
    bf16* __restrict__ hproj,
    float* __restrict__ asrc, float* __restrict__ adst,
    const int* __restrict__ flag)
{
  __shared__ bf16 sA[64*LDA];    // 17.0 KB
  __shared__ bf16 sB[128*LDB];   // 34.0 KB
  int f32 = *flag;
  int t = threadIdx.x;
  int n0 = blockIdx.x*64;

  // stage WT (bf16, [n][k]) -> sB. 128x128 bf16 = 2048 uint4; 16 chunks/row.
  {
    const uint4* srcv = (const uint4*)(WT + wtoff);
    #pragma unroll
    for (int i=0;i<8;i++){
      int u4 = t + 256*i;          // 0..2047
      int row = u4 >> 4, c = u4 & 15;
      *(uint4*)(&sB[row*LDB + c*8]) = srcv[u4];
    }
  }
  // stage A: residual rows n0..n0+63 -> bf16 sA
  {
    #pragma unroll
    for (int i=0;i<16;i++){
      int pidx = t + 256*i;        // pair index 0..4095
      int row = pidx >> 6, colp = pidx & 63;
      int gr = n0 + row;
      float2 v = make_float2(0.f, 0.f);
      if (gr < NN) v = res_ld2(residF, dout, f32, (size_t)gr*DD + colp*2);
      sA[row*LDA + colp*2]     = __float2bfloat16(v.x);
      sA[row*LDA + colp*2 + 1] = __float2bfloat16(v.y);
    }
  }
  __syncthreads();

  int wv = t >> 6, lane = t & 63;
  int m = lane & 15, kq = lane >> 4;      // kq = 0..3
  int rowbase = wv*16;

  f32x4 acc[8];
  #pragma unroll
  for (int nt=0; nt<8; nt++) acc[nt] = (f32x4){0.f,0.f,0.f,0.f};

  #pragma unroll
  for (int ks=0; ks<4; ks++){
    short8 afrag = *(const short8*)(&sA[(rowbase + m)*LDA + ks*32 + kq*8]);
    #pragma unroll
    for (int nt=0; nt<8; nt++){
      short8 bfrag = *(const short8*)(&sB[(nt*16 + m)*LDB + ks*32 + kq*8]);
      acc[nt] = __builtin_amdgcn_mfma_f32_16x16x32_bf16(afrag, bfrag, acc[nt], 0, 0, 0);
    }
  }

  // store C -> hproj (bf16). C/D layout: col = lane&15, row = kq*4 + reg
  #pragma unroll
  for (int reg=0; reg<4; reg++){
    int gr = n0 + rowbase + kq*4 + reg;
    if (gr < NN){
      bf16* dst = hproj + (size_t)gr*DD + m;
      #pragma unroll
      for (int nt=0; nt<8; nt++)
        dst[nt*16] = __float2bfloat16(acc[nt][reg]);
    }
  }

  // fused alpha: per-lane a-vector values at col = nt*16 + m
  float avs[8], avd[8];
  #pragma unroll
  for (int nt=0; nt<8; nt++){
    avs[nt] = in_ld(aws, aoff + nt*16 + m, f32);
    avd[nt] = in_ld(awd, aoff + nt*16 + m, f32);
  }
  #pragma unroll
  for (int h=0; h<4; h++){
    #pragma unroll
    for (int reg=0; reg<4; reg++){
      float ps = acc[2*h][reg]*avs[2*h] + acc[2*h+1][reg]*avs[2*h+1];
      float pd = acc[2*h][reg]*avd[2*h] + acc[2*h+1][reg]*avd[2*h+1];
      #pragma unroll
      for (int off=1; off<16; off<<=1){
        ps += __shfl_xor(ps, off);
        pd += __shfl_xor(pd, off);
      }
      if (m == 0){
        int gr = n0 + rowbase + kq*4 + reg;
        if (gr < NN){
          asrc[gr*NH + h] = ps;
          adst[gr*NH + h] = pd;
        }
      }
    }
  }
}

// ---------------- attention aggregation + LN + ELU + residual ----------------
__device__ __forceinline__ float4 edge_e(const float4 as, const float4 ad){
  float4 l, e;
  l.x = as.x + ad.x; l.y = as.y + ad.y; l.z = as.z + ad.z; l.w = as.w + ad.w;
  l.x = l.x > 0.f ? l.x : 0.2f*l.x;
  l.y = l.y > 0.f ? l.y : 0.2f*l.y;
  l.z = l.z > 0.f ? l.z : 0.2f*l.z;
  l.w = l.w > 0.f ? l.w : 0.2f*l.w;
  l.x = fminf(l.x, 30.f); l.y = fminf(l.y, 30.f);   // firewall: true logits <= ~10
  l.z = fminf(l.z, 30.f); l.w = fminf(l.w, 30.f);
  e.x = __expf(l.x); e.y = __expf(l.y); e.z = __expf(l.z); e.w = __expf(l.w);
  return e;
}

__device__ __forceinline__ float2 hp_ld2(const void* hp, int s, int lane){
  unsigned int hv = ((const unsigned int*)hp)[(size_t)s*64 + lane];
  return make_float2(__uint_as_float(hv << 16), __uint_as_float(hv & 0xFFFF0000u));
}

__global__ __launch_bounds__(256) void k_agg(const bf16* __restrict__ hproj,
    const float* __restrict__ asrc, const float* __restrict__ adst,
    const int* __restrict__ offs, const int* __restrict__ csr,
    float* __restrict__ residF, void* __restrict__ dout,
    const void* __restrict__ bias, size_t boff,
    const void* __restrict__ lng, const void* __restrict__ lnb, size_t lnoff,
    const int* __restrict__ flag, const int first)
{
  __shared__ float s_al[4][256];
  int f32 = *flag;
  int wid = threadIdx.x >> 6, lane = threadIdx.x & 63;
  int n = blockIdx.x*4 + wid;        // NN % 4 == 0
  int beg = offs[n];
  int end = offs[n+1];
  beg = max(0, min(beg, EP));
  end = max(beg, min(end, EP));
  int deg = min(end - beg, 1024);    // firewall; true max deg ~50
  const float4 ad = ((const float4*)adst)[n];
  int head = lane >> 4;
  float2 a0c = make_float2(0.f,0.f), a1c = make_float2(0.f,0.f);
  float2 a2c = make_float2(0.f,0.f), a3c = make_float2(0.f,0.f);

  if (deg <= 64){
    float4 e = make_float4(0,0,0,0);
    int sreg = 0;
    if (lane < deg){
      unsigned int us = (unsigned int)csr[beg+lane];
      if (us >= NN) us = 0;          // firewall
      sreg = (int)us;
      float4 as = ((const float4*)asrc)[sreg];
      e = edge_e(as, ad);
    }
    float4 zs = e;
    #pragma unroll
    for (int off=32; off>0; off>>=1){
      zs.x += __shfl_down(zs.x, off);
      zs.y += __shfl_down(zs.y, off);
      zs.z += __shfl_down(zs.z, off);
      zs.w += __shfl_down(zs.w, off);
    }
    float4 invz;
    invz.x = 1.f/(__shfl(zs.x,0)+1e-16f);
    invz.y = 1.f/(__shfl(zs.y,0)+1e-16f);
    invz.z = 1.f/(__shfl(zs.z,0)+1e-16f);
    invz.w = 1.f/(__shfl(zs.w,0)+1e-16f);
    if (lane < deg){
      s_al[wid][lane*4+0] = e.x*invz.x;
      s_al[wid][lane*4+1] = e.y*invz.y;
      s_al[wid][lane*4+2] = e.z*invz.z;
      s_al[wid][lane*4+3] = e.w*invz.w;
    }
    __threadfence_block();
    // unrolled x4: 4 independent gather loads in flight per wave
    int t = 0;
    for (; t+4 <= deg; t += 4){
      int s0 = __shfl(sreg, t+0), s1 = __shfl(sreg, t+1);
      int s2 = __shfl(sreg, t+2), s3 = __shfl(sreg, t+3);
      float2 v0 = hp_ld2(hproj, s0, lane);
      float2 v1 = hp_ld2(hproj, s1, lane);
      float2 v2 = hp_ld2(hproj, s2, lane);
      float2 v3 = hp_ld2(hproj, s3, lane);
      float al0 = s_al[wid][(t+0)*4+head];
      float al1 = s_al[wid][(t+1)*4+head];
      float al2 = s_al[wid][(t+2)*4+head];
      float al3 = s_al[wid][(t+3)*4+head];
      a0c.x += v0.x*al0; a0c.y += v0.y*al0;
      a1c.x += v1.x*al1; a1c.y += v1.y*al1;
      a2c.x += v2.x*al2; a2c.y += v2.y*al2;
      a3c.x += v3.x*al3; a3c.y += v3.y*al3;
    }
    for (; t < deg; t++){
      int s = __shfl(sreg, t);
      float a = s_al[wid][t*4+head];
      float2 hv = hp_ld2(hproj, s, lane);
      a0c.x += hv.x*a;
      a0c.y += hv.y*a;
    }
  } else {
    float4 zs = make_float4(0,0,0,0);
    for (int j=lane; j<deg; j+=64){
      unsigned int us = (unsigned int)csr[beg+j];
      if (us >= NN) us = 0;
      float4 as = ((const float4*)asrc)[us];
      float4 e = edge_e(as, ad);
      zs.x+=e.x; zs.y+=e.y; zs.z+=e.z; zs.w+=e.w;
    }
    #pragma unroll
    for (int off=32; off>0; off>>=1){
      zs.x += __shfl_down(zs.x, off);
      zs.y += __shfl_down(zs.y, off);
      zs.z += __shfl_down(zs.z, off);
      zs.w += __shfl_down(zs.w, off);
    }
    float4 invz;
    invz.x = 1.f/(__shfl(zs.x,0)+1e-16f);
    invz.y = 1.f/(__shfl(zs.y,0)+1e-16f);
    invz.z = 1.f/(__shfl(zs.z,0)+1e-16f);
    invz.w = 1.f/(__shfl(zs.w,0)+1e-16f);
    int nch = (deg+63)>>6;
    for (int c2=0;c2<nch;c2++){
      int base = c2<<6, j = base+lane;
      int sreg = 0;
      __threadfence_block();
      if (j < deg){
        unsigned int us = (unsigned int)csr[beg+j];
        if (us >= NN) us = 0;
        sreg = (int)us;
        float4 as = ((const float4*)asrc)[sreg];
        float4 e = edge_e(as, ad);
        s_al[wid][lane*4+0]=e.x*invz.x;
        s_al[wid][lane*4+1]=e.y*invz.y;
        s_al[wid][lane*4+2]=e.z*invz.z;
        s_al[wid][lane*4+3]=e.w*invz.w;
      }
      __threadfence_block();
      int cnt = min(64, deg-base);
      for (int t=0;t<cnt;t++){
        int s = __shfl(sreg, t);
        float a = s_al[wid][t*4+head];
        float2 hv = hp_ld2(hproj, s, lane);
        a0c.x += hv.x*a;
        a0c.y += hv.y*a;
      }
    }
  }

  float2 acc = make_float2(a0c.x + a1c.x + a2c.x + a3c.x,
                           a0c.y + a1c.y + a2c.y + a3c.y);

  // epilogue: bias + layernorm + elu + residual
  float vx = acc.x + in_ld(bias, boff + 2*lane,   f32);
  float vy = acc.y + in_ld(bias, boff + 2*lane+1, f32);
  float s1 = vx+vy, s2 = vx*vx+vy*vy;
  #pragma unroll
  for (int off=32; off>0; off>>=1){
    s1 += __shfl_down(s1, off);
    s2 += __shfl_down(s2, off);
  }
  float mean = __shfl(s1,0) * (1.f/DD);
  float msq  = __shfl(s2,0) * (1.f/DD);
  float var  = fmaxf(msq - mean*mean, 0.f);
  float r = rsqrtf(var + 1e-5f);
  float yx = (vx-mean)*r*in_ld(lng, lnoff+2*lane,   f32) + in_ld(lnb, lnoff+2*lane,   f32);
  float yy = (vy-mean)*r*in_ld(lng, lnoff+2*lane+1, f32) + in_ld(lnb, lnoff+2*lane+1, f32);
  yx = yx>0.f ? yx : expm1f(yx);
  yy = yy>0.f ? yy : expm1f(yy);
  float2 res;
  if (first){
    res = make_float2(yx, yy);
  } else {
    float px = res_ld(residF, dout, f32, (size_t)n*DD + 2*lane);
    float py = res_ld(residF, dout, f32, (size_t)n*DD + 2*lane + 1);
    res = make_float2(px+yx, py+yy);
  }
  if (residF){
    ((float2*)residF)[(size_t)n*64+lane] = res;
  } else if (f32){
    ((float2*)dout)[(size_t)n*64+lane] = res;
  } else {
    bf16* q = (bf16*)dout;
    q[(size_t)n*DD + 2*lane]     = __float2bfloat16(res.x);
    q[(size_t)n*DD + 2*lane + 1] = __float2bfloat16(res.y);
  }
}

// ---------------- pooling ----------------
__global__ __launch_bounds__(128) void k_pool(const float* __restrict__ residF, void* __restrict__ dout,
    const int* __restrict__ batch, float* __restrict__ gsum, int* __restrict__ gcnt,
    const int* __restrict__ flag){
  __shared__ int sb[64];
  int f32 = *flag;
  int d = threadIdx.x;
  int n0 = blockIdx.x*64;
  int cnt = min(64, NN - n0);
  if (d < cnt){
    unsigned int b = (unsigned int)batch[n0 + d];
    if (b >= NG) b = 0;            // firewall
    sb[d] = (int)b;
  }
  __syncthreads();
  float local = 0.f;
  int cur = sb[0];
  for (int i=0;i<cnt;i++){
    int b = sb[i];
    if (b != cur){
      atomicAdd(&gsum[cur*DD + d], local);
      local = 0.f; cur = b;
    }
    size_t idx = (size_t)(n0+i)*DD + d;
    float v = res_ld(residF, dout, f32, idx);
    if (residF){
      if (f32) ((float*)dout)[idx] = v;
      else     ((bf16*)dout)[idx] = __float2bfloat16(v);
    }
    local += v;
  }
  atomicAdd(&gsum[cur*DD + d], local);
  if (d == 0){
    int lc = 0; int c2 = sb[0];
    for (int i=0;i<cnt;i++){
      int b = sb[i];
      if (b != c2){ atomicAdd(&gcnt[c2], lc); lc = 0; c2 = b; }
      lc++;
    }
    atomicAdd(&gcnt[c2], lc);
  }
}

__global__ __launch_bounds__(128) void k_final(const float* __restrict__ gsum, const int* __restrict__ gcnt,
                                               void* __restrict__ dout, const int* __restrict__ flag){
  int f32 = *flag;
  int i = blockIdx.x*128 + threadIdx.x;
  if (i < NG*DD){
    float c = (float)gcnt[i>>7];
    if (c < 1.f) c = 1.f;
    float val = gsum[i] / c;
    if (f32) ((float*)dout)[(size_t)NN*DD + i] = val;
    else     ((bf16*)dout)[(size_t)NN*DD + i] = __float2bfloat16(val);
  }
}

extern "C" void kernel_launch(void* const* d_in, const int* in_sizes, int n_in,
                              void* d_out, int out_size, void* d_ws, size_t ws_size,
                              hipStream_t stream){
  const void* x      = d_in[0];
  const int*  ei     = (const int*) d_in[1];
  const int*  batch  = (const int*) d_in[2];
  const void* W0     = d_in[3];
  const void* asrc0  = d_in[4];
  const void* adst0  = d_in[5];
  const void* b0     = d_in[6];
  const void* Ws     = d_in[7];
  const void* asrcs  = d_in[8];
  const void* adsts  = d_in[9];
  const void* bs     = d_in[10];
  const void* lng    = d_in[11];
  const void* lnb    = d_in[12];

  const int* srcs = ei;
  const int* dsts = ei + NE;

  uintptr_t p0 = (uintptr_t)d_ws;
  uintptr_t p = p0;
  auto alloc = [&](size_t bytes)->void* {
    void* r = (void*)p; p += (bytes + 255) & ~(size_t)255; return r;
  };
  // fixed pool (~24.7 MB)
  int*   csr    = (int*)  alloc((size_t)EP*4);
  int*   offs   = (int*)  alloc((size_t)(NN+1)*4);
  float* asrc   = (float*)alloc((size_t)NN*NH*4);
  float* adst   = (float*)alloc((size_t)NN*NH*4);
  int*   deg    = (int*)  alloc((size_t)NN*4);
  int*   cursor = (int*)  alloc((size_t)NN*4);
  int*   incl   = (int*)  alloc((size_t)NN*4);
  int*   bsum   = (int*)  alloc(512*4);
  int*   bex    = (int*)  alloc(512*4);
  float* gsum   = (float*)alloc((size_t)NG*DD*4);
  int*   gcnt   = (int*)  alloc(NG*4);
  int*   flag   = (int*)  alloc(256);
  int*   bcur   = (int*)  alloc((size_t)NBUK*4);
  int2*  gstag  = (int2*) alloc((size_t)NE*8);        // 12.8 MB bucketed edge staging
  bf16*  wt     = (bf16*) alloc((size_t)3*DD*DD*2);   // 96 KB, transposed layer weights

  // hproj always bf16 (25.6 MB)
  bf16* hproj = (bf16*)alloc((size_t)NN*DD*2);

  size_t used = (size_t)(p - p0);
  size_t rem  = (ws_size > used) ? (ws_size - used) : 0;
  const size_t RESB = (size_t)NN*DD*4;   // 51.2 MB
  float* residF = nullptr;
  if (rem >= RESB + 4096) residF = (float*)alloc(RESB);   // fp32 residual if it fits

  const int NB = (NN + 255)/256; // 391

  k_init<<<NB, 256, 0, stream>>>(deg, cursor, gsum, gcnt, (const unsigned int*)x, flag);
  k_hist<<<NHB + 3, 256, 0, stream>>>(dsts, deg, Ws, wt, flag);
  k_scan1<<<NB, 256, 0, stream>>>(deg, incl, bsum);
  k_scan2<<<1, 512, 0, stream>>>(bsum, bex, NB);
  k_scan3<<<NB, 256, 0, stream>>>(incl, bex, offs);
  k_binit<<<1, 256, 0, stream>>>(offs, bcur);
  k_bin<<<(NE+4095)/4096, 256, 0, stream>>>(srcs, dsts, bcur, gstag);
  k_bucket<<<NBUK, 256, 0, stream>>>(offs, gstag, csr, cursor);

  const int GEMM_B = (NN + 63)/64;  // 1563

  for (int l=0; l<4; l++){
    if (l == 0){
      k_gemm0<<<NN/4, 128, 0, stream>>>(x, W0, asrc0, adst0, hproj, asrc, adst, flag);
      k_agg<<<NN/4, 256, 0, stream>>>(hproj, asrc, adst, offs, csr, residF, d_out,
                                      b0, 0, lng, lnb, 0, flag, 1);
    } else {
      size_t wtoff = (size_t)(l-1)*DD*DD;
      size_t aoff  = (size_t)(l-1)*DD;
      k_gemm_mfma<<<GEMM_B, 256, 0, stream>>>(residF, d_out, wt, wtoff,
                                              asrcs, adsts, aoff,
                                              hproj, asrc, adst, flag);
      k_agg<<<NN/4, 256, 0, stream>>>(hproj, asrc, adst, offs, csr, residF, d_out,
                                      bs, (size_t)(l-1)*DD, lng, lnb, (size_t)l*DD, flag, 0);
    }
  }

  k_pool<<<(NN+63)/64, 128, 0, stream>>>(residF, d_out, batch, gsum, gcnt, flag);
  k_final<<<(NG*DD+127)/128, 128, 0, stream>>>(gsum, gcnt, d_out, flag);
}

// Round 12
// 726.277 us; speedup vs baseline: 1.1875x; 1.0498x over previous
//
#include <hip/hip_runtime.h>
#include <hip/hip_bf16.h>

#define NN 100000
#define NE 1600000
#define EP (NE + NN)      // 1700000 edges incl self loops
#define NH 4
#define NC 32
#define DD 128
#define NG 64
#define NIN 7

#define BSH 9                       // bucket = dst >> 9 (512 nodes/bucket)
#define NBUK ((NN + 511) >> BSH)    // 196
#define SEGCAP 9600                 // CSR segment cap (mean 8704, sigma ~90)
#define NHB ((NE + 255)/256)        // 6250 hist blocks

typedef __hip_bfloat16 bf16;
typedef __attribute__((ext_vector_type(8))) short short8;
typedef __attribute__((ext_vector_type(4))) float f32x4;

__device__ __forceinline__ float b2f(const bf16 v){ return __bfloat162float(v); }

// flag-steered input load: f32 ? fp32 tensor : bf16 tensor
__device__ __forceinline__ float in_ld(const void* p, size_t i, int f32){
  return f32 ? ((const float*)p)[i] : b2f(((const bf16*)p)[i]);
}

__device__ __forceinline__ unsigned int bfbits(float v){
  bf16 b = __float2bfloat16(v);
  return (unsigned int)(*(unsigned short*)&b);
}

// ---------------- init (+ dtype sniffer in block 0) ----------------
__global__ __launch_bounds__(256) void k_init(int* __restrict__ deg, int* __restrict__ cursor,
                                              float* __restrict__ gsum, int* __restrict__ gcnt,
                                              const unsigned int* __restrict__ xb, int* __restrict__ flag){
  int i = blockIdx.x*256 + threadIdx.x;
  if (i < NN){ deg[i] = 1; cursor[i] = 1; }   // deg=1: self loop (slot 0); cursor starts past it
  if (i < NG*DD) gsum[i] = 0.f;
  if (i < NG) gcnt[i] = 0;
  if (blockIdx.x == 0 && threadIdx.x < 64){
    int t = threadIdx.x;
    int pl = 0;
    for (int j = t; j < 512; j += 64){
      float v = __uint_as_float(xb[j]);
      float a = fabsf(v);
      if (v == v && a < 1e6f && a > 1e-10f) pl++;
    }
    #pragma unroll
    for (int off = 32; off > 0; off >>= 1) pl += __shfl_down(pl, off);
    if (t == 0) *flag = (pl >= 384) ? 1 : 0;   // >=75% plausible => fp32
  }
}

// ---------------- CSR build (+ W-transpose prep in tail blocks) ----------------
__global__ __launch_bounds__(256) void k_hist(const int* __restrict__ dst, int* __restrict__ deg,
                                              const void* __restrict__ Ws, bf16* __restrict__ WT,
                                              const int* __restrict__ flag){
  if (blockIdx.x >= NHB){
    // WT[n][k] = W[k][n], bf16 — 3 layers, one block each
    int l = blockIdx.x - NHB;   // 0..2
    int f32 = *flag;            // written by k_init (prior launch, stream-ordered)
    for (int idx = threadIdx.x; idx < DD*DD; idx += 256){
      int n = idx >> 7, k = idx & 127;
      WT[(size_t)l*DD*DD + idx] = __float2bfloat16(in_ld(Ws, (size_t)l*DD*DD + (size_t)k*DD + n, f32));
    }
    return;
  }
  int e = blockIdx.x*256 + threadIdx.x;
  if (e < NE){
    unsigned int d = (unsigned int)dst[e];
    if (d < NN) atomicAdd(&deg[d], 1);
  }
}

__global__ __launch_bounds__(256) void k_scan1(const int* __restrict__ deg, int* __restrict__ incl,
                                               int* __restrict__ bsum){
  __shared__ int tmp[256];
  int t = threadIdx.x, i = blockIdx.x*256 + t;
  int v = (i < NN) ? deg[i] : 0;
  tmp[t] = v; __syncthreads();
  for (int off=1; off<256; off<<=1){
    int a = (t >= off) ? tmp[t-off] : 0;
    __syncthreads();
    tmp[t] += a;
    __syncthreads();
  }
  if (i < NN) incl[i] = tmp[t];
  if (t == 255) bsum[blockIdx.x] = tmp[255];
}

__global__ __launch_bounds__(512) void k_scan2(const int* __restrict__ bsum, int* __restrict__ bex, int nb){
  __shared__ int tmp[512];
  int t = threadIdx.x;
  int v = (t < nb) ? bsum[t] : 0;
  tmp[t] = v; __syncthreads();
  for (int off=1; off<512; off<<=1){
    int a = (t >= off) ? tmp[t-off] : 0;
    __syncthreads();
    tmp[t] += a;
    __syncthreads();
  }
  if (t < nb) bex[t] = tmp[t] - v;  // exclusive block prefix
}

__global__ __launch_bounds__(256) void k_scan3(const int* __restrict__ incl, const int* __restrict__ bex,
                                               int* __restrict__ offs){
  int i = blockIdx.x*256 + threadIdx.x;
  if (i < NN) offs[i+1] = incl[i] + bex[i>>8];
  if (i == 0) offs[0] = 0;
}

// staging base per bucket: offs[b*512] - b*512 (each node has exactly 1 self loop)
__global__ __launch_bounds__(256) void k_binit(const int* __restrict__ offs, int* __restrict__ bcur){
  int b = threadIdx.x + blockIdx.x*256;
  if (b < NBUK){
    int ns = b << BSH;
    bcur[b] = offs[ns] - ns;
  }
}

// Pass 2: bin 4096 edges/block by dst-bucket in LDS, append runs to staging
__global__ __launch_bounds__(256) void k_bin(const int* __restrict__ src, const int* __restrict__ dst,
                                             int* __restrict__ bcur, int2* __restrict__ gstag){
  __shared__ int cnt[NBUK], pref[NBUK+1], place[NBUK], gbase[NBUK];
  __shared__ int2 pairs[4096];   // 32 KB
  int tid = threadIdx.x;
  for (int b = tid; b < NBUK; b += 256){ cnt[b]=0; place[b]=0; }
  __syncthreads();
  int e0 = blockIdx.x*4096;
  int s[16], d[16];
  #pragma unroll
  for (int i=0;i<16;i++){
    int e = e0 + i*256 + tid;
    s[i] = 0; d[i] = -1;
    if (e < NE){
      unsigned int us = (unsigned int)src[e]; if (us >= NN) us = 0;   // firewall
      unsigned int ud = (unsigned int)dst[e]; if (ud >= NN) ud = 0;   // firewall
      s[i] = (int)us; d[i] = (int)ud;
      atomicAdd(&cnt[ud>>BSH], 1);
    }
  }
  __syncthreads();
  if (tid == 0){
    int run = 0;
    for (int b=0;b<NBUK;b++){ pref[b] = run; run += cnt[b]; }
    pref[NBUK] = run;
  }
  __syncthreads();
  for (int b = tid; b < NBUK; b += 256){
    if (cnt[b] > 0) gbase[b] = atomicAdd(&bcur[b], cnt[b]);
  }
  __syncthreads();
  #pragma unroll
  for (int i=0;i<16;i++){
    if (d[i] >= 0){
      int b = d[i]>>BSH;
      int lp = atomicAdd(&place[b],1);
      pairs[pref[b]+lp] = make_int2(s[i], d[i]);
    }
  }
  __syncthreads();
  int tot = pref[NBUK];
  for (int j = tid; j < tot; j += 256){
    int2 pr = pairs[j];
    int b = pr.y>>BSH;
    int gidx = gbase[b] + (j - pref[b]);
    if (gidx >= 0 && gidx < NE) gstag[gidx] = pr;   // firewall
  }
}

// Pass 3: per-bucket CSR segment built in LDS, streamed out coalesced
__global__ __launch_bounds__(256) void k_bucket(const int* __restrict__ offs,
                                                const int2* __restrict__ gstag,
                                                int* __restrict__ csr, int* __restrict__ cursor){
  __shared__ int seg[SEGCAP];   // 37.5 KB
  __shared__ int lcur[512];
  int b = blockIdx.x, tid = threadIdx.x;
  int nstart = b << BSH;
  int nend = min(nstart + 512, NN);
  int nloc = nend - nstart;
  int base = offs[nstart];
  int segN = offs[nend] - base;
  if (segN < 0) segN = 0;
  int ecnt = segN - nloc; if (ecnt < 0) ecnt = 0;
  int estart = base - nstart;          // staging offset of this bucket
  if (segN <= SEGCAP){
    for (int ln = tid; ln < nloc; ln += 256){
      lcur[ln] = 1;
      int p = offs[nstart+ln] - base;
      if (p >= 0 && p < SEGCAP) seg[p] = nstart + ln;     // self loop at slot 0
    }
    __syncthreads();
    for (int j = tid; j < ecnt; j += 256){
      int sidx = estart + j;
      int2 pr = (sidx >= 0 && sidx < NE) ? gstag[sidx] : make_int2(0, nstart);
      int ln = pr.y - nstart;
      if (ln < 0 || ln >= nloc) ln = 0;                   // firewall
      int p = atomicAdd(&lcur[ln], 1);
      int idx = offs[nstart+ln] - base + p;
      if (idx >= 0 && idx < SEGCAP) seg[idx] = pr.x;
    }
    __syncthreads();
    for (int j = tid; j < segN; j += 256) csr[base + j] = seg[j];
  } else {
    // slow path (unreachable for this input): direct global scatter
    for (int ln = tid; ln < nloc; ln += 256){
      int p = offs[nstart+ln];
      if (p >= 0 && p < EP) csr[p] = nstart + ln;
    }
    __syncthreads();
    for (int j = tid; j < ecnt; j += 256){
      int sidx = estart + j;
      int2 pr = (sidx >= 0 && sidx < NE) ? gstag[sidx] : make_int2(0, nstart);
      unsigned int dd = (unsigned int)pr.y; if (dd >= NN) dd = 0;
      int p = atomicAdd(&cursor[dd], 1);
      int idx = offs[dd] + p;
      if (idx >= 0 && idx < EP) csr[idx] = pr.x;
    }
  }
}

// ---------------- layer-0 projection (IN_DIM=7) + alpha ----------------
__device__ __forceinline__ void alpha_red(float acc, float was, float wad, int d, int n,
                                          float* __restrict__ asrc, float* __restrict__ adst){
  float ps = acc*was, pd = acc*wad;
  #pragma unroll
  for (int off=16; off>0; off>>=1){
    ps += __shfl_down(ps, off, 32);
    pd += __shfl_down(pd, off, 32);
  }
  if ((d & 31) == 0){
    asrc[n*NH + (d>>5)] = ps;
    adst[n*NH + (d>>5)] = pd;
  }
}

__global__ __launch_bounds__(128) void k_gemm0(const void* __restrict__ x, const void* __restrict__ W,
    const void* __restrict__ aws, const void* __restrict__ awd,
    bf16* __restrict__ hproj,
    float* __restrict__ asrc, float* __restrict__ adst, const int* __restrict__ flag){
  int f32 = *flag;
  __shared__ float xr[4][NIN];
  int d = threadIdx.x;
  int n0 = blockIdx.x*4;
  if (d < 4*NIN) xr[d/NIN][d%NIN] = in_ld(x, (size_t)n0*NIN + d, f32);
  __syncthreads();
  float a0=0,a1=0,a2=0,a3=0;
  #pragma unroll
  for (int k=0;k<NIN;k++){
    float w = in_ld(W, (size_t)k*DD + d, f32);
    a0 += xr[0][k]*w; a1 += xr[1][k]*w; a2 += xr[2][k]*w; a3 += xr[3][k]*w;
  }
  hproj[(size_t)(n0+0)*DD+d]=__float2bfloat16(a0);
  hproj[(size_t)(n0+1)*DD+d]=__float2bfloat16(a1);
  hproj[(size_t)(n0+2)*DD+d]=__float2bfloat16(a2);
  hproj[(size_t)(n0+3)*DD+d]=__float2bfloat16(a3);
  float was = in_ld(aws, d, f32), wad = in_ld(awd, d, f32);
  alpha_red(a0, was, wad, d, n0+0, asrc, adst);
  alpha_red(a1, was, wad, d, n0+1, asrc, adst);
  alpha_red(a2, was, wad, d, n0+2, asrc, adst);
  alpha_red(a3, was, wad, d, n0+3, asrc, adst);
}

// ---------------- layers 1..3: MFMA GEMM (64 rows/block) + fused alpha ----------------
// LDS rows padded to 136 elements (272 B): b128 frag reads land 2 lanes/bank (free).
#define LDA 136
#define LDB 136

__global__ __launch_bounds__(256) void k_gemm_mfma(
    const bf16* __restrict__ resid,           // bf16 residual stream in ws
    const bf16* __restrict__ WT, size_t wtoff,
    const void* __restrict__ aws, const void* __restrict__ awd, size_t aoff,
    bf16* __restrict__ hproj,
    float* __restrict__ asrc, float* __restrict__ adst,
    const int* __restrict__ flag)
{
  __shared__ bf16 sA[64*LDA];    // 17.0 KB
  __shared__ bf16 sB[128*LDB];   // 34.0 KB
  int f32 = *flag;
  int t = threadIdx.x;
  int n0 = blockIdx.x*64;

  // stage WT (bf16, [n][k]) -> sB. 128x128 bf16 = 2048 uint4; 16 chunks/row.
  {
    const uint4* srcv = (const uint4*)(WT + wtoff);
    #pragma unroll
    for (int i=0;i<8;i++){
      int u4 = t + 256*i;          // 0..2047
      int row = u4 >> 4, c = u4 & 15;
      *(uint4*)(&sB[row*LDB + c*8]) = srcv[u4];
    }
  }
  // stage A: bf16 residual rows n0..n0+63 -> sA (pure uint4 copy; row = 16 uint4)
  {
    const uint4* av = (const uint4*)resid;
    #pragma unroll
    for (int i=0;i<4;i++){
      int u4 = t + 256*i;          // 0..1023
      int row = u4 >> 4, c = u4 & 15;
      int gr = n0 + row;
      uint4 v = make_uint4(0,0,0,0);
      if (gr < NN) v = av[(size_t)gr*16 + c];
      *(uint4*)(&sA[row*LDA + c*8]) = v;
    }
  }
  __syncthreads();

  int wv = t >> 6, lane = t & 63;
  int m = lane & 15, kq = lane >> 4;      // kq = 0..3
  int rowbase = wv*16;

  f32x4 acc[8];
  #pragma unroll
  for (int nt=0; nt<8; nt++) acc[nt] = (f32x4){0.f,0.f,0.f,0.f};

  #pragma unroll
  for (int ks=0; ks<4; ks++){
    short8 afrag = *(const short8*)(&sA[(rowbase + m)*LDA + ks*32 + kq*8]);
    #pragma unroll
    for (int nt=0; nt<8; nt++){
      short8 bfrag = *(const short8*)(&sB[(nt*16 + m)*LDB + ks*32 + kq*8]);
      acc[nt] = __builtin_amdgcn_mfma_f32_16x16x32_bf16(afrag, bfrag, acc[nt], 0, 0, 0);
    }
  }

  // store C -> hproj (bf16). C/D layout: col = lane&15, row = kq*4 + reg
  #pragma unroll
  for (int reg=0; reg<4; reg++){
    int gr = n0 + rowbase + kq*4 + reg;
    if (gr < NN){
      bf16* dst = hproj + (size_t)gr*DD + m;
      #pragma unroll
      for (int nt=0; nt<8; nt++)
        dst[nt*16] = __float2bfloat16(acc[nt][reg]);
    }
  }

  // fused alpha: per-lane a-vector values at col = nt*16 + m
  float avs[8], avd[8];
  #pragma unroll
  for (int nt=0; nt<8; nt++){
    avs[nt] = in_ld(aws, aoff + nt*16 + m, f32);
    avd[nt] = in_ld(awd, aoff + nt*16 + m, f32);
  }
  #pragma unroll
  for (int h=0; h<4; h++){
    #pragma unroll
    for (int reg=0; reg<4; reg++){
      float ps = acc[2*h][reg]*avs[2*h] + acc[2*h+1][reg]*avs[2*h+1];
      float pd = acc[2*h][reg]*avd[2*h] + acc[2*h+1][reg]*avd[2*h+1];
      #pragma unroll
      for (int off=1; off<16; off<<=1){
        ps += __shfl_xor(ps, off);
        pd += __shfl_xor(pd, off);
      }
      if (m == 0){
        int gr = n0 + rowbase + kq*4 + reg;
        if (gr < NN){
          asrc[gr*NH + h] = ps;
          adst[gr*NH + h] = pd;
        }
      }
    }
  }
}

// ---------------- attention aggregation + LN + ELU + residual ----------------
__device__ __forceinline__ float4 edge_e(const float4 as, const float4 ad){
  float4 l, e;
  l.x = as.x + ad.x; l.y = as.y + ad.y; l.z = as.z + ad.z; l.w = as.w + ad.w;
  l.x = l.x > 0.f ? l.x : 0.2f*l.x;
  l.y = l.y > 0.f ? l.y : 0.2f*l.y;
  l.z = l.z > 0.f ? l.z : 0.2f*l.z;
  l.w = l.w > 0.f ? l.w : 0.2f*l.w;
  l.x = fminf(l.x, 30.f); l.y = fminf(l.y, 30.f);   // firewall: true logits <= ~10
  l.z = fminf(l.z, 30.f); l.w = fminf(l.w, 30.f);
  e.x = __expf(l.x); e.y = __expf(l.y); e.z = __expf(l.z); e.w = __expf(l.w);
  return e;
}

__device__ __forceinline__ float2 hp_ld2(const void* hp, int s, int lane){
  unsigned int hv = ((const unsigned int*)hp)[(size_t)s*64 + lane];
  return make_float2(__uint_as_float(hv << 16), __uint_as_float(hv & 0xFFFF0000u));
}

__global__ __launch_bounds__(256) void k_agg(const bf16* __restrict__ hproj,
    const float* __restrict__ asrc, const float* __restrict__ adst,
    const int* __restrict__ offs, const int* __restrict__ csr,
    bf16* __restrict__ resid,
    const void* __restrict__ bias, size_t boff,
    const void* __restrict__ lng, const void* __restrict__ lnb, size_t lnoff,
    const int* __restrict__ flag, const int first)
{
  __shared__ float s_al[4][256];
  int f32 = *flag;
  int wid = threadIdx.x >> 6, lane = threadIdx.x & 63;
  int n = blockIdx.x*4 + wid;        // NN % 4 == 0
  int beg = offs[n];
  int end = offs[n+1];
  beg = max(0, min(beg, EP));
  end = max(beg, min(end, EP));
  int deg = min(end - beg, 1024);    // firewall; true max deg ~50
  const float4 ad = ((const float4*)adst)[n];
  int head = lane >> 4;
  float2 a0c = make_float2(0.f,0.f), a1c = make_float2(0.f,0.f);
  float2 a2c = make_float2(0.f,0.f), a3c = make_float2(0.f,0.f);

  if (deg <= 64){
    float4 e = make_float4(0,0,0,0);
    int sreg = 0;
    if (lane < deg){
      unsigned int us = (unsigned int)csr[beg+lane];
      if (us >= NN) us = 0;          // firewall
      sreg = (int)us;
      float4 as = ((const float4*)asrc)[sreg];
      e = edge_e(as, ad);
    }
    float4 zs = e;
    #pragma unroll
    for (int off=32; off>0; off>>=1){
      zs.x += __shfl_down(zs.x, off);
      zs.y += __shfl_down(zs.y, off);
      zs.z += __shfl_down(zs.z, off);
      zs.w += __shfl_down(zs.w, off);
    }
    float4 invz;
    invz.x = 1.f/(__shfl(zs.x,0)+1e-16f);
    invz.y = 1.f/(__shfl(zs.y,0)+1e-16f);
    invz.z = 1.f/(__shfl(zs.z,0)+1e-16f);
    invz.w = 1.f/(__shfl(zs.w,0)+1e-16f);
    if (lane < deg){
      s_al[wid][lane*4+0] = e.x*invz.x;
      s_al[wid][lane*4+1] = e.y*invz.y;
      s_al[wid][lane*4+2] = e.z*invz.z;
      s_al[wid][lane*4+3] = e.w*invz.w;
    }
    __threadfence_block();
    // unrolled x4: 4 independent gather loads in flight per wave
    int t = 0;
    for (; t+4 <= deg; t += 4){
      int s0 = __shfl(sreg, t+0), s1 = __shfl(sreg, t+1);
      int s2 = __shfl(sreg, t+2), s3 = __shfl(sreg, t+3);
      float2 v0 = hp_ld2(hproj, s0, lane);
      float2 v1 = hp_ld2(hproj, s1, lane);
      float2 v2 = hp_ld2(hproj, s2, lane);
      float2 v3 = hp_ld2(hproj, s3, lane);
      float al0 = s_al[wid][(t+0)*4+head];
      float al1 = s_al[wid][(t+1)*4+head];
      float al2 = s_al[wid][(t+2)*4+head];
      float al3 = s_al[wid][(t+3)*4+head];
      a0c.x += v0.x*al0; a0c.y += v0.y*al0;
      a1c.x += v1.x*al1; a1c.y += v1.y*al1;
      a2c.x += v2.x*al2; a2c.y += v2.y*al2;
      a3c.x += v3.x*al3; a3c.y += v3.y*al3;
    }
    for (; t < deg; t++){
      int s = __shfl(sreg, t);
      float a = s_al[wid][t*4+head];
      float2 hv = hp_ld2(hproj, s, lane);
      a0c.x += hv.x*a;
      a0c.y += hv.y*a;
    }
  } else {
    float4 zs = make_float4(0,0,0,0);
    for (int j=lane; j<deg; j+=64){
      unsigned int us = (unsigned int)csr[beg+j];
      if (us >= NN) us = 0;
      float4 as = ((const float4*)asrc)[us];
      float4 e = edge_e(as, ad);
      zs.x+=e.x; zs.y+=e.y; zs.z+=e.z; zs.w+=e.w;
    }
    #pragma unroll
    for (int off=32; off>0; off>>=1){
      zs.x += __shfl_down(zs.x, off);
      zs.y += __shfl_down(zs.y, off);
      zs.z += __shfl_down(zs.z, off);
      zs.w += __shfl_down(zs.w, off);
    }
    float4 invz;
    invz.x = 1.f/(__shfl(zs.x,0)+1e-16f);
    invz.y = 1.f/(__shfl(zs.y,0)+1e-16f);
    invz.z = 1.f/(__shfl(zs.z,0)+1e-16f);
    invz.w = 1.f/(__shfl(zs.w,0)+1e-16f);
    int nch = (deg+63)>>6;
    for (int c2=0;c2<nch;c2++){
      int base = c2<<6, j = base+lane;
      int sreg = 0;
      __threadfence_block();
      if (j < deg){
        unsigned int us = (unsigned int)csr[beg+j];
        if (us >= NN) us = 0;
        sreg = (int)us;
        float4 as = ((const float4*)asrc)[sreg];
        float4 e = edge_e(as, ad);
        s_al[wid][lane*4+0]=e.x*invz.x;
        s_al[wid][lane*4+1]=e.y*invz.y;
        s_al[wid][lane*4+2]=e.z*invz.z;
        s_al[wid][lane*4+3]=e.w*invz.w;
      }
      __threadfence_block();
      int cnt = min(64, deg-base);
      for (int t=0;t<cnt;t++){
        int s = __shfl(sreg, t);
        float a = s_al[wid][t*4+head];
        float2 hv = hp_ld2(hproj, s, lane);
        a0c.x += hv.x*a;
        a0c.y += hv.y*a;
      }
    }
  }

  float2 acc = make_float2(a0c.x + a1c.x + a2c.x + a3c.x,
                           a0c.y + a1c.y + a2c.y + a3c.y);

  // epilogue: bias + layernorm + elu + residual (residual stream is bf16 in ws)
  float vx = acc.x + in_ld(bias, boff + 2*lane,   f32);
  float vy = acc.y + in_ld(bias, boff + 2*lane+1, f32);
  float s1 = vx+vy, s2 = vx*vx+vy*vy;
  #pragma unroll
  for (int off=32; off>0; off>>=1){
    s1 += __shfl_down(s1, off);
    s2 += __shfl_down(s2, off);
  }
  float mean = __shfl(s1,0) * (1.f/DD);
  float msq  = __shfl(s2,0) * (1.f/DD);
  float var  = fmaxf(msq - mean*mean, 0.f);
  float r = rsqrtf(var + 1e-5f);
  float yx = (vx-mean)*r*in_ld(lng, lnoff+2*lane,   f32) + in_ld(lnb, lnoff+2*lane,   f32);
  float yy = (vy-mean)*r*in_ld(lng, lnoff+2*lane+1, f32) + in_ld(lnb, lnoff+2*lane+1, f32);
  yx = yx>0.f ? yx : expm1f(yx);
  yy = yy>0.f ? yy : expm1f(yy);
  float2 res;
  if (first){
    res = make_float2(yx, yy);
  } else {
    unsigned int pu = ((const unsigned int*)resid)[(size_t)n*64 + lane];
    res = make_float2(__uint_as_float(pu << 16) + yx,
                      __uint_as_float(pu & 0xFFFF0000u) + yy);
  }
  unsigned int pk = bfbits(res.x) | (bfbits(res.y) << 16);
  ((unsigned int*)resid)[(size_t)n*64 + lane] = pk;
}

// ---------------- pooling (reads bf16 residual, writes node embeddings to d_out) ----------------
__global__ __launch_bounds__(128) void k_pool(const bf16* __restrict__ resid, void* __restrict__ dout,
    const int* __restrict__ batch, float* __restrict__ gsum, int* __restrict__ gcnt,
    const int* __restrict__ flag){
  __shared__ int sb[64];
  int f32 = *flag;
  int d = threadIdx.x;
  int n0 = blockIdx.x*64;
  int cnt = min(64, NN - n0);
  if (d < cnt){
    unsigned int b = (unsigned int)batch[n0 + d];
    if (b >= NG) b = 0;            // firewall
    sb[d] = (int)b;
  }
  __syncthreads();
  float local = 0.f;
  int cur = sb[0];
  for (int i=0;i<cnt;i++){
    int b = sb[i];
    if (b != cur){
      atomicAdd(&gsum[cur*DD + d], local);
      local = 0.f; cur = b;
    }
    size_t idx = (size_t)(n0+i)*DD + d;
    float v = b2f(resid[idx]);
    if (f32) ((float*)dout)[idx] = v;
    else     ((bf16*)dout)[idx] = resid[idx];
    local += v;
  }
  atomicAdd(&gsum[cur*DD + d], local);
  if (d == 0){
    int lc = 0; int c2 = sb[0];
    for (int i=0;i<cnt;i++){
      int b = sb[i];
      if (b != c2){ atomicAdd(&gcnt[c2], lc); lc = 0; c2 = b; }
      lc++;
    }
    atomicAdd(&gcnt[c2], lc);
  }
}

__global__ __launch_bounds__(128) void k_final(const float* __restrict__ gsum, const int* __restrict__ gcnt,
                                               void* __restrict__ dout, const int* __restrict__ flag){
  int f32 = *flag;
  int i = blockIdx.x*128 + threadIdx.x;
  if (i < NG*DD){
    float c = (float)gcnt[i>>7];
    if (c < 1.f) c = 1.f;
    float val = gsum[i] / c;
    if (f32) ((float*)dout)[(size_t)NN*DD + i] = val;
    else     ((bf16*)dout)[(size_t)NN*DD + i] = __float2bfloat16(val);
  }
}

extern "C" void kernel_launch(void* const* d_in, const int* in_sizes, int n_in,
                              void* d_out, int out_size, void* d_ws, size_t ws_size,
                              hipStream_t stream){
  const void* x      = d_in[0];
  const int*  ei     = (const int*) d_in[1];
  const int*  batch  = (const int*) d_in[2];
  const void* W0     = d_in[3];
  const void* asrc0  = d_in[4];
  const void* adst0  = d_in[5];
  const void* b0     = d_in[6];
  const void* Ws     = d_in[7];
  const void* asrcs  = d_in[8];
  const void* adsts  = d_in[9];
  const void* bs     = d_in[10];
  const void* lng    = d_in[11];
  const void* lnb    = d_in[12];

  const int* srcs = ei;
  const int* dsts = ei + NE;

  uintptr_t p0 = (uintptr_t)d_ws;
  uintptr_t p = p0;
  auto alloc = [&](size_t bytes)->void* {
    void* r = (void*)p; p += (bytes + 255) & ~(size_t)255; return r;
  };
  // fixed pool (~24.7 MB)
  int*   csr    = (int*)  alloc((size_t)EP*4);
  int*   offs   = (int*)  alloc((size_t)(NN+1)*4);
  float* asrc   = (float*)alloc((size_t)NN*NH*4);
  float* adst   = (float*)alloc((size_t)NN*NH*4);
  int*   deg    = (int*)  alloc((size_t)NN*4);
  int*   cursor = (int*)  alloc((size_t)NN*4);
  int*   incl   = (int*)  alloc((size_t)NN*4);
  int*   bsum   = (int*)  alloc(512*4);
  int*   bex    = (int*)  alloc(512*4);
  float* gsum   = (float*)alloc((size_t)NG*DD*4);
  int*   gcnt   = (int*)  alloc(NG*4);
  int*   flag   = (int*)  alloc(256);
  int*   bcur   = (int*)  alloc((size_t)NBUK*4);
  int2*  gstag  = (int2*) alloc((size_t)NE*8);        // 12.8 MB bucketed edge staging
  bf16*  wt     = (bf16*) alloc((size_t)3*DD*DD*2);   // 96 KB, transposed layer weights

  bf16* hproj = (bf16*)alloc((size_t)NN*DD*2);        // 25.6 MB
  bf16* resid = (bf16*)alloc((size_t)NN*DD*2);        // 25.6 MB residual stream (bf16)

  const int NB = (NN + 255)/256; // 391

  k_init<<<NB, 256, 0, stream>>>(deg, cursor, gsum, gcnt, (const unsigned int*)x, flag);
  k_hist<<<NHB + 3, 256, 0, stream>>>(dsts, deg, Ws, wt, flag);
  k_scan1<<<NB, 256, 0, stream>>>(deg, incl, bsum);
  k_scan2<<<1, 512, 0, stream>>>(bsum, bex, NB);
  k_scan3<<<NB, 256, 0, stream>>>(incl, bex, offs);
  k_binit<<<1, 256, 0, stream>>>(offs, bcur);
  k_bin<<<(NE+4095)/4096, 256, 0, stream>>>(srcs, dsts, bcur, gstag);
  k_bucket<<<NBUK, 256, 0, stream>>>(offs, gstag, csr, cursor);

  const int GEMM_B = (NN + 63)/64;  // 1563

  for (int l=0; l<4; l++){
    if (l == 0){
      k_gemm0<<<NN/4, 128, 0, stream>>>(x, W0, asrc0, adst0, hproj, asrc, adst, flag);
      k_agg<<<NN/4, 256, 0, stream>>>(hproj, asrc, adst, offs, csr, resid,
                                      b0, 0, lng, lnb, 0, flag, 1);
    } else {
      size_t wtoff = (size_t)(l-1)*DD*DD;
      size_t aoff  = (size_t)(l-1)*DD;
      k_gemm_mfma<<<GEMM_B, 256, 0, stream>>>(resid, wt, wtoff,
                                              asrcs, adsts, aoff,
                                              hproj, asrc, adst, flag);
      k_agg<<<NN/4, 256, 0, stream>>>(hproj, asrc, adst, offs, csr, resid,
                                      bs, (size_t)(l-1)*DD, lng, lnb, (size_t)l*DD, flag, 0);
    }
  }

  k_pool<<<(NN+63)/64, 128, 0, stream>>>(resid, d_out, batch, gsum, gcnt, flag);
  k_final<<<(NG*DD+127)/128, 128, 0, stream>>>(gsum, gcnt, d_out, flag);
}

// Round 13
// 642.799 us; speedup vs baseline: 1.3417x; 1.1299x over previous
//
#include <hip/hip_runtime.h>
#include <hip/hip_bf16.h>

#define NN 100000
#define NE 1600000
#define NH 4
#define NC 32
#define DD 128
#define NG 64
#define NIN 7

#define BSH 9                       // bucket = dst >> 9 (512 nodes/bucket)
#define NBUK ((NN + 511) >> BSH)    // 196
#define SEGCAP 9600                 // CSR per-bucket stride (mean 8704, +10 sigma)
#define CAPE (SEGCAP - 512)         // 9088 staged edges/bucket max -> segN <= SEGCAP always
#define CSRN (NBUK * SEGCAP)        // 1881600 csr entries
#define NBBIN ((NE + 4095)/4096)    // 391 binning blocks

typedef __hip_bfloat16 bf16;
typedef __attribute__((ext_vector_type(8))) short short8;
typedef __attribute__((ext_vector_type(4))) float f32x4;

__device__ __forceinline__ float b2f(const bf16 v){ return __bfloat162float(v); }

// flag-steered input load: f32 ? fp32 tensor : bf16 tensor
__device__ __forceinline__ float in_ld(const void* p, size_t i, int f32){
  return f32 ? ((const float*)p)[i] : b2f(((const bf16*)p)[i]);
}

__device__ __forceinline__ unsigned int bfbits(float v){
  bf16 b = __float2bfloat16(v);
  return (unsigned int)(*(unsigned short*)&b);
}

// ---------------- init (+ dtype sniffer in block 0) ----------------
__global__ __launch_bounds__(256) void k_init(float* __restrict__ gsum, int* __restrict__ gcnt,
                                              int* __restrict__ bcur,
                                              const unsigned int* __restrict__ xb, int* __restrict__ flag){
  int i = blockIdx.x*256 + threadIdx.x;
  if (i < NG*DD) gsum[i] = 0.f;
  if (i < NG) gcnt[i] = 0;
  if (i < NBUK) bcur[i] = i * CAPE;          // fixed-stride staging base
  if (blockIdx.x == 0 && threadIdx.x < 64){
    int t = threadIdx.x;
    int pl = 0;
    for (int j = t; j < 512; j += 64){
      float v = __uint_as_float(xb[j]);
      float a = fabsf(v);
      if (v == v && a < 1e6f && a > 1e-10f) pl++;
    }
    #pragma unroll
    for (int off = 32; off > 0; off >>= 1) pl += __shfl_down(pl, off);
    if (t == 0) *flag = (pl >= 384) ? 1 : 0;   // >=75% plausible => fp32
  }
}

// ---------------- Pass 1: bin 4096 edges/block by dst-bucket (+ W-prep tail blocks) ----------------
__global__ __launch_bounds__(256) void k_bin(const int* __restrict__ src, const int* __restrict__ dst,
                                             int* __restrict__ bcur, int2* __restrict__ gstag,
                                             const void* __restrict__ Ws, bf16* __restrict__ WT,
                                             const int* __restrict__ flag){
  if (blockIdx.x >= NBBIN){
    // WT[n][k] = W[k][n], bf16 — 3 layers, one block each
    int l = blockIdx.x - NBBIN;   // 0..2
    int f32 = *flag;              // written by k_init (prior launch, stream-ordered)
    for (int idx = threadIdx.x; idx < DD*DD; idx += 256){
      int n = idx >> 7, k = idx & 127;
      WT[(size_t)l*DD*DD + idx] = __float2bfloat16(in_ld(Ws, (size_t)l*DD*DD + (size_t)k*DD + n, f32));
    }
    return;
  }
  __shared__ int cnt[NBUK], pref[NBUK+1], place[NBUK], gbase[NBUK];
  __shared__ int2 pairs[4096];   // 32 KB
  int tid = threadIdx.x;
  for (int b = tid; b < NBUK; b += 256){ cnt[b]=0; place[b]=0; }
  __syncthreads();
  int e0 = blockIdx.x*4096;
  int s[16], d[16];
  #pragma unroll
  for (int i=0;i<16;i++){
    int e = e0 + i*256 + tid;
    s[i] = 0; d[i] = -1;
    if (e < NE){
      unsigned int us = (unsigned int)src[e]; if (us >= NN) us = 0;   // firewall
      unsigned int ud = (unsigned int)dst[e]; if (ud >= NN) ud = 0;   // firewall
      s[i] = (int)us; d[i] = (int)ud;
      atomicAdd(&cnt[ud>>BSH], 1);
    }
  }
  __syncthreads();
  if (tid == 0){
    int run = 0;
    for (int b=0;b<NBUK;b++){ pref[b] = run; run += cnt[b]; }
    pref[NBUK] = run;
  }
  __syncthreads();
  for (int b = tid; b < NBUK; b += 256){
    if (cnt[b] > 0) gbase[b] = atomicAdd(&bcur[b], cnt[b]);
  }
  __syncthreads();
  #pragma unroll
  for (int i=0;i<16;i++){
    if (d[i] >= 0){
      int b = d[i]>>BSH;
      int lp = atomicAdd(&place[b],1);
      pairs[pref[b]+lp] = make_int2(s[i], d[i]);
    }
  }
  __syncthreads();
  int tot = pref[NBUK];
  for (int j = tid; j < tot; j += 256){
    int2 pr = pairs[j];
    int b = pr.y>>BSH;
    int gidx = gbase[b] + (j - pref[b]);
    // firewall: stay inside bucket b's staging strip
    if (gidx >= b*CAPE && gidx < (b+1)*CAPE) gstag[gidx] = pr;
  }
}

// ---------------- Pass 2: per-bucket count + scan + CSR segment in LDS ----------------
__global__ __launch_bounds__(256) void k_bucket(const int2* __restrict__ gstag,
                                                const int* __restrict__ bcur,
                                                int* __restrict__ csr,
                                                int* __restrict__ offs, int* __restrict__ oend){
  __shared__ int seg[SEGCAP];    // 37.5 KB
  __shared__ int lcnt[512];
  __shared__ int loff[512];
  __shared__ int pscan[256];
  int b = blockIdx.x, tid = threadIdx.x;
  int nstart = b << BSH;
  int nend = min(nstart + 512, NN);
  int nloc = nend - nstart;
  int base = b * SEGCAP;
  int stbase = b * CAPE;
  int ecnt = bcur[b] - stbase;
  ecnt = max(0, min(ecnt, CAPE));
  // counts: 1 (self loop) per valid node
  lcnt[tid]     = (tid < nloc) ? 1 : 0;
  lcnt[tid+256] = (tid+256 < nloc) ? 1 : 0;
  __syncthreads();
  for (int j = tid; j < ecnt; j += 256){
    int2 pr = gstag[stbase + j];
    int ln = pr.y - nstart;
    if (ln < 0 || ln >= nloc) ln = 0;   // firewall
    atomicAdd(&lcnt[ln], 1);
  }
  __syncthreads();
  // scan over 512 via pair-sum + Hillis-Steele on 256
  int c0 = lcnt[2*tid], c1 = lcnt[2*tid+1];
  int pairsum = c0 + c1;
  pscan[tid] = pairsum;
  __syncthreads();
  for (int off=1; off<256; off<<=1){
    int a = (tid >= off) ? pscan[tid-off] : 0;
    __syncthreads();
    pscan[tid] += a;
    __syncthreads();
  }
  int pexcl = pscan[tid] - pairsum;
  loff[2*tid]   = pexcl;
  loff[2*tid+1] = pexcl + c0;
  __syncthreads();
  int segN = pscan[255];
  if (segN > SEGCAP) segN = SEGCAP;     // structurally impossible; firewall
  // write offs/oend, place self loops, reset cursors
  if (tid < nloc){
    offs[nstart + tid] = base + loff[tid];
    oend[nstart + tid] = base + loff[tid] + lcnt[tid];
  }
  if (tid + 256 < nloc){
    offs[nstart + tid + 256] = base + loff[tid+256];
    oend[nstart + tid + 256] = base + loff[tid+256] + lcnt[tid+256];
  }
  __syncthreads();
  if (tid < nloc){ int p = loff[tid]; if (p < SEGCAP) seg[p] = nstart + tid; lcnt[tid] = 1; }
  if (tid + 256 < nloc){ int p = loff[tid+256]; if (p < SEGCAP) seg[p] = nstart + tid + 256; lcnt[tid+256] = 1; }
  __syncthreads();
  for (int j = tid; j < ecnt; j += 256){
    int2 pr = gstag[stbase + j];
    int ln = pr.y - nstart;
    if (ln < 0 || ln >= nloc) ln = 0;
    int p = atomicAdd(&lcnt[ln], 1);
    int idx = loff[ln] + p;
    if (idx >= 0 && idx < SEGCAP) seg[idx] = pr.x;
  }
  __syncthreads();
  for (int j = tid; j < segN; j += 256) csr[base + j] = seg[j];
}

// ---------------- layer-0 projection (IN_DIM=7) + alpha ----------------
__device__ __forceinline__ void alpha_red(float acc, float was, float wad, int d, int n,
                                          float* __restrict__ asrc, float* __restrict__ adst){
  float ps = acc*was, pd = acc*wad;
  #pragma unroll
  for (int off=16; off>0; off>>=1){
    ps += __shfl_down(ps, off, 32);
    pd += __shfl_down(pd, off, 32);
  }
  if ((d & 31) == 0){
    asrc[n*NH + (d>>5)] = ps;
    adst[n*NH + (d>>5)] = pd;
  }
}

__global__ __launch_bounds__(128) void k_gemm0(const void* __restrict__ x, const void* __restrict__ W,
    const void* __restrict__ aws, const void* __restrict__ awd,
    bf16* __restrict__ hproj,
    float* __restrict__ asrc, float* __restrict__ adst, const int* __restrict__ flag){
  int f32 = *flag;
  __shared__ float xr[4][NIN];
  int d = threadIdx.x;
  int n0 = blockIdx.x*4;
  if (d < 4*NIN) xr[d/NIN][d%NIN] = in_ld(x, (size_t)n0*NIN + d, f32);
  __syncthreads();
  float a0=0,a1=0,a2=0,a3=0;
  #pragma unroll
  for (int k=0;k<NIN;k++){
    float w = in_ld(W, (size_t)k*DD + d, f32);
    a0 += xr[0][k]*w; a1 += xr[1][k]*w; a2 += xr[2][k]*w; a3 += xr[3][k]*w;
  }
  hproj[(size_t)(n0+0)*DD+d]=__float2bfloat16(a0);
  hproj[(size_t)(n0+1)*DD+d]=__float2bfloat16(a1);
  hproj[(size_t)(n0+2)*DD+d]=__float2bfloat16(a2);
  hproj[(size_t)(n0+3)*DD+d]=__float2bfloat16(a3);
  float was = in_ld(aws, d, f32), wad = in_ld(awd, d, f32);
  alpha_red(a0, was, wad, d, n0+0, asrc, adst);
  alpha_red(a1, was, wad, d, n0+1, asrc, adst);
  alpha_red(a2, was, wad, d, n0+2, asrc, adst);
  alpha_red(a3, was, wad, d, n0+3, asrc, adst);
}

// ---------------- layers 1..3: MFMA GEMM (64 rows/block) + fused alpha ----------------
// LDS rows padded to 136 elements (272 B): b128 frag reads land 2 lanes/bank (free).
#define LDA 136
#define LDB 136

__global__ __launch_bounds__(256) void k_gemm_mfma(
    const bf16* __restrict__ resid,           // bf16 residual stream in ws
    const bf16* __restrict__ WT, size_t wtoff,
    const void* __restrict__ aws, const void* __restrict__ awd, size_t aoff,
    bf16* __restrict__ hproj,
    float* __restrict__ asrc, float* __restrict__ adst,
    const int* __restrict__ flag)
{
  __shared__ bf16 sA[64*LDA];    // 17.0 KB
  __shared__ bf16 sB[128*LDB];   // 34.0 KB
  int f32 = *flag;
  int t = threadIdx.x;
  int n0 = blockIdx.x*64;

  // stage WT (bf16, [n][k]) -> sB. 128x128 bf16 = 2048 uint4; 16 chunks/row.
  {
    const uint4* srcv = (const uint4*)(WT + wtoff);
    #pragma unroll
    for (int i=0;i<8;i++){
      int u4 = t + 256*i;          // 0..2047
      int row = u4 >> 4, c = u4 & 15;
      *(uint4*)(&sB[row*LDB + c*8]) = srcv[u4];
    }
  }
  // stage A: bf16 residual rows n0..n0+63 -> sA (pure uint4 copy; row = 16 uint4)
  {
    const uint4* av = (const uint4*)resid;
    #pragma unroll
    for (int i=0;i<4;i++){
      int u4 = t + 256*i;          // 0..1023
      int row = u4 >> 4, c = u4 & 15;
      int gr = n0 + row;
      uint4 v = make_uint4(0,0,0,0);
      if (gr < NN) v = av[(size_t)gr*16 + c];
      *(uint4*)(&sA[row*LDA + c*8]) = v;
    }
  }
  __syncthreads();

  int wv = t >> 6, lane = t & 63;
  int m = lane & 15, kq = lane >> 4;      // kq = 0..3
  int rowbase = wv*16;

  f32x4 acc[8];
  #pragma unroll
  for (int nt=0; nt<8; nt++) acc[nt] = (f32x4){0.f,0.f,0.f,0.f};

  #pragma unroll
  for (int ks=0; ks<4; ks++){
    short8 afrag = *(const short8*)(&sA[(rowbase + m)*LDA + ks*32 + kq*8]);
    #pragma unroll
    for (int nt=0; nt<8; nt++){
      short8 bfrag = *(const short8*)(&sB[(nt*16 + m)*LDB + ks*32 + kq*8]);
      acc[nt] = __builtin_amdgcn_mfma_f32_16x16x32_bf16(afrag, bfrag, acc[nt], 0, 0, 0);
    }
  }

  // store C -> hproj (bf16). C/D layout: col = lane&15, row = kq*4 + reg
  #pragma unroll
  for (int reg=0; reg<4; reg++){
    int gr = n0 + rowbase + kq*4 + reg;
    if (gr < NN){
      bf16* dst = hproj + (size_t)gr*DD + m;
      #pragma unroll
      for (int nt=0; nt<8; nt++)
        dst[nt*16] = __float2bfloat16(acc[nt][reg]);
    }
  }

  // fused alpha: per-lane a-vector values at col = nt*16 + m
  float avs[8], avd[8];
  #pragma unroll
  for (int nt=0; nt<8; nt++){
    avs[nt] = in_ld(aws, aoff + nt*16 + m, f32);
    avd[nt] = in_ld(awd, aoff + nt*16 + m, f32);
  }
  #pragma unroll
  for (int h=0; h<4; h++){
    #pragma unroll
    for (int reg=0; reg<4; reg++){
      float ps = acc[2*h][reg]*avs[2*h] + acc[2*h+1][reg]*avs[2*h+1];
      float pd = acc[2*h][reg]*avd[2*h] + acc[2*h+1][reg]*avd[2*h+1];
      #pragma unroll
      for (int off=1; off<16; off<<=1){
        ps += __shfl_xor(ps, off);
        pd += __shfl_xor(pd, off);
      }
      if (m == 0){
        int gr = n0 + rowbase + kq*4 + reg;
        if (gr < NN){
          asrc[gr*NH + h] = ps;
          adst[gr*NH + h] = pd;
        }
      }
    }
  }
}

// ---------------- attention aggregation + LN + ELU + residual ----------------
__device__ __forceinline__ float4 edge_e(const float4 as, const float4 ad){
  float4 l, e;
  l.x = as.x + ad.x; l.y = as.y + ad.y; l.z = as.z + ad.z; l.w = as.w + ad.w;
  l.x = l.x > 0.f ? l.x : 0.2f*l.x;
  l.y = l.y > 0.f ? l.y : 0.2f*l.y;
  l.z = l.z > 0.f ? l.z : 0.2f*l.z;
  l.w = l.w > 0.f ? l.w : 0.2f*l.w;
  l.x = fminf(l.x, 30.f); l.y = fminf(l.y, 30.f);   // firewall: true logits <= ~10
  l.z = fminf(l.z, 30.f); l.w = fminf(l.w, 30.f);
  e.x = __expf(l.x); e.y = __expf(l.y); e.z = __expf(l.z); e.w = __expf(l.w);
  return e;
}

__device__ __forceinline__ float2 hp_ld2(const void* hp, int s, int lane){
  unsigned int hv = ((const unsigned int*)hp)[(size_t)s*64 + lane];
  return make_float2(__uint_as_float(hv << 16), __uint_as_float(hv & 0xFFFF0000u));
}

__global__ __launch_bounds__(256) void k_agg(const bf16* __restrict__ hproj,
    const float* __restrict__ asrc, const float* __restrict__ adst,
    const int* __restrict__ offs, const int* __restrict__ oend, const int* __restrict__ csr,
    bf16* __restrict__ resid,
    const void* __restrict__ bias, size_t boff,
    const void* __restrict__ lng, const void* __restrict__ lnb, size_t lnoff,
    const int* __restrict__ flag, const int first)
{
  __shared__ float s_al[4][256];
  int f32 = *flag;
  int wid = threadIdx.x >> 6, lane = threadIdx.x & 63;
  int n = blockIdx.x*4 + wid;        // NN % 4 == 0
  int beg = offs[n];
  int end = oend[n];
  beg = max(0, min(beg, CSRN));
  end = max(beg, min(end, CSRN));
  int deg = min(end - beg, 1024);    // firewall; true max deg ~50
  const float4 ad = ((const float4*)adst)[n];
  int head = lane >> 4;
  float2 a0c = make_float2(0.f,0.f), a1c = make_float2(0.f,0.f);
  float2 a2c = make_float2(0.f,0.f), a3c = make_float2(0.f,0.f);

  if (deg <= 64){
    float4 e = make_float4(0,0,0,0);
    int sreg = 0;
    if (lane < deg){
      unsigned int us = (unsigned int)csr[beg+lane];
      if (us >= NN) us = 0;          // firewall
      sreg = (int)us;
      float4 as = ((const float4*)asrc)[sreg];
      e = edge_e(as, ad);
    }
    float4 zs = e;
    #pragma unroll
    for (int off=32; off>0; off>>=1){
      zs.x += __shfl_down(zs.x, off);
      zs.y += __shfl_down(zs.y, off);
      zs.z += __shfl_down(zs.z, off);
      zs.w += __shfl_down(zs.w, off);
    }
    float4 invz;
    invz.x = 1.f/(__shfl(zs.x,0)+1e-16f);
    invz.y = 1.f/(__shfl(zs.y,0)+1e-16f);
    invz.z = 1.f/(__shfl(zs.z,0)+1e-16f);
    invz.w = 1.f/(__shfl(zs.w,0)+1e-16f);
    if (lane < deg){
      s_al[wid][lane*4+0] = e.x*invz.x;
      s_al[wid][lane*4+1] = e.y*invz.y;
      s_al[wid][lane*4+2] = e.z*invz.z;
      s_al[wid][lane*4+3] = e.w*invz.w;
    }
    __threadfence_block();
    // unrolled x4: 4 independent gather loads in flight per wave
    int t = 0;
    for (; t+4 <= deg; t += 4){
      int s0 = __shfl(sreg, t+0), s1 = __shfl(sreg, t+1);
      int s2 = __shfl(sreg, t+2), s3 = __shfl(sreg, t+3);
      float2 v0 = hp_ld2(hproj, s0, lane);
      float2 v1 = hp_ld2(hproj, s1, lane);
      float2 v2 = hp_ld2(hproj, s2, lane);
      float2 v3 = hp_ld2(hproj, s3, lane);
      float al0 = s_al[wid][(t+0)*4+head];
      float al1 = s_al[wid][(t+1)*4+head];
      float al2 = s_al[wid][(t+2)*4+head];
      float al3 = s_al[wid][(t+3)*4+head];
      a0c.x += v0.x*al0; a0c.y += v0.y*al0;
      a1c.x += v1.x*al1; a1c.y += v1.y*al1;
      a2c.x += v2.x*al2; a2c.y += v2.y*al2;
      a3c.x += v3.x*al3; a3c.y += v3.y*al3;
    }
    for (; t < deg; t++){
      int s = __shfl(sreg, t);
      float a = s_al[wid][t*4+head];
      float2 hv = hp_ld2(hproj, s, lane);
      a0c.x += hv.x*a;
      a0c.y += hv.y*a;
    }
  } else {
    float4 zs = make_float4(0,0,0,0);
    for (int j=lane; j<deg; j+=64){
      unsigned int us = (unsigned int)csr[beg+j];
      if (us >= NN) us = 0;
      float4 as = ((const float4*)asrc)[us];
      float4 e = edge_e(as, ad);
      zs.x+=e.x; zs.y+=e.y; zs.z+=e.z; zs.w+=e.w;
    }
    #pragma unroll
    for (int off=32; off>0; off>>=1){
      zs.x += __shfl_down(zs.x, off);
      zs.y += __shfl_down(zs.y, off);
      zs.z += __shfl_down(zs.z, off);
      zs.w += __shfl_down(zs.w, off);
    }
    float4 invz;
    invz.x = 1.f/(__shfl(zs.x,0)+1e-16f);
    invz.y = 1.f/(__shfl(zs.y,0)+1e-16f);
    invz.z = 1.f/(__shfl(zs.z,0)+1e-16f);
    invz.w = 1.f/(__shfl(zs.w,0)+1e-16f);
    int nch = (deg+63)>>6;
    for (int c2=0;c2<nch;c2++){
      int base = c2<<6, j = base+lane;
      int sreg = 0;
      __threadfence_block();
      if (j < deg){
        unsigned int us = (unsigned int)csr[beg+j];
        if (us >= NN) us = 0;
        sreg = (int)us;
        float4 as = ((const float4*)asrc)[sreg];
        float4 e = edge_e(as, ad);
        s_al[wid][lane*4+0]=e.x*invz.x;
        s_al[wid][lane*4+1]=e.y*invz.y;
        s_al[wid][lane*4+2]=e.z*invz.z;
        s_al[wid][lane*4+3]=e.w*invz.w;
      }
      __threadfence_block();
      int cnt = min(64, deg-base);
      for (int t=0;t<cnt;t++){
        int s = __shfl(sreg, t);
        float a = s_al[wid][t*4+head];
        float2 hv = hp_ld2(hproj, s, lane);
        a0c.x += hv.x*a;
        a0c.y += hv.y*a;
      }
    }
  }

  float2 acc = make_float2(a0c.x + a1c.x + a2c.x + a3c.x,
                           a0c.y + a1c.y + a2c.y + a3c.y);

  // epilogue: bias + layernorm + elu + residual (residual stream is bf16 in ws)
  float vx = acc.x + in_ld(bias, boff + 2*lane,   f32);
  float vy = acc.y + in_ld(bias, boff + 2*lane+1, f32);
  float s1 = vx+vy, s2 = vx*vx+vy*vy;
  #pragma unroll
  for (int off=32; off>0; off>>=1){
    s1 += __shfl_down(s1, off);
    s2 += __shfl_down(s2, off);
  }
  float mean = __shfl(s1,0) * (1.f/DD);
  float msq  = __shfl(s2,0) * (1.f/DD);
  float var  = fmaxf(msq - mean*mean, 0.f);
  float r = rsqrtf(var + 1e-5f);
  float yx = (vx-mean)*r*in_ld(lng, lnoff+2*lane,   f32) + in_ld(lnb, lnoff+2*lane,   f32);
  float yy = (vy-mean)*r*in_ld(lng, lnoff+2*lane+1, f32) + in_ld(lnb, lnoff+2*lane+1, f32);
  yx = yx>0.f ? yx : expm1f(yx);
  yy = yy>0.f ? yy : expm1f(yy);
  float2 res;
  if (first){
    res = make_float2(yx, yy);
  } else {
    unsigned int pu = ((const unsigned int*)resid)[(size_t)n*64 + lane];
    res = make_float2(__uint_as_float(pu << 16) + yx,
                      __uint_as_float(pu & 0xFFFF0000u) + yy);
  }
  unsigned int pk = bfbits(res.x) | (bfbits(res.y) << 16);
  ((unsigned int*)resid)[(size_t)n*64 + lane] = pk;
}

// ---------------- pooling (reads bf16 residual, writes node embeddings to d_out) ----------------
__global__ __launch_bounds__(128) void k_pool(const bf16* __restrict__ resid, void* __restrict__ dout,
    const int* __restrict__ batch, float* __restrict__ gsum, int* __restrict__ gcnt,
    const int* __restrict__ flag){
  __shared__ int sb[64];
  int f32 = *flag;
  int d = threadIdx.x;
  int n0 = blockIdx.x*64;
  int cnt = min(64, NN - n0);
  if (d < cnt){
    unsigned int b = (unsigned int)batch[n0 + d];
    if (b >= NG) b = 0;            // firewall
    sb[d] = (int)b;
  }
  __syncthreads();
  float local = 0.f;
  int cur = sb[0];
  for (int i=0;i<cnt;i++){
    int b = sb[i];
    if (b != cur){
      atomicAdd(&gsum[cur*DD + d], local);
      local = 0.f; cur = b;
    }
    size_t idx = (size_t)(n0+i)*DD + d;
    float v = b2f(resid[idx]);
    if (f32) ((float*)dout)[idx] = v;
    else     ((bf16*)dout)[idx] = resid[idx];
    local += v;
  }
  atomicAdd(&gsum[cur*DD + d], local);
  if (d == 0){
    int lc = 0; int c2 = sb[0];
    for (int i=0;i<cnt;i++){
      int b = sb[i];
      if (b != c2){ atomicAdd(&gcnt[c2], lc); lc = 0; c2 = b; }
      lc++;
    }
    atomicAdd(&gcnt[c2], lc);
  }
}

__global__ __launch_bounds__(128) void k_final(const float* __restrict__ gsum, const int* __restrict__ gcnt,
                                               void* __restrict__ dout, const int* __restrict__ flag){
  int f32 = *flag;
  int i = blockIdx.x*128 + threadIdx.x;
  if (i < NG*DD){
    float c = (float)gcnt[i>>7];
    if (c < 1.f) c = 1.f;
    float val = gsum[i] / c;
    if (f32) ((float*)dout)[(size_t)NN*DD + i] = val;
    else     ((bf16*)dout)[(size_t)NN*DD + i] = __float2bfloat16(val);
  }
}

extern "C" void kernel_launch(void* const* d_in, const int* in_sizes, int n_in,
                              void* d_out, int out_size, void* d_ws, size_t ws_size,
                              hipStream_t stream){
  const void* x      = d_in[0];
  const int*  ei     = (const int*) d_in[1];
  const int*  batch  = (const int*) d_in[2];
  const void* W0     = d_in[3];
  const void* asrc0  = d_in[4];
  const void* adst0  = d_in[5];
  const void* b0     = d_in[6];
  const void* Ws     = d_in[7];
  const void* asrcs  = d_in[8];
  const void* adsts  = d_in[9];
  const void* bs     = d_in[10];
  const void* lng    = d_in[11];
  const void* lnb    = d_in[12];

  const int* srcs = ei;
  const int* dsts = ei + NE;

  uintptr_t p0 = (uintptr_t)d_ws;
  uintptr_t p = p0;
  auto alloc = [&](size_t bytes)->void* {
    void* r = (void*)p; p += (bytes + 255) & ~(size_t)255; return r;
  };
  int*   csr    = (int*)  alloc((size_t)CSRN*4);        // 7.5 MB fixed-stride CSR
  int*   offs   = (int*)  alloc((size_t)NN*4);
  int*   oend   = (int*)  alloc((size_t)NN*4);
  float* asrc   = (float*)alloc((size_t)NN*NH*4);
  float* adst   = (float*)alloc((size_t)NN*NH*4);
  float* gsum   = (float*)alloc((size_t)NG*DD*4);
  int*   gcnt   = (int*)  alloc(NG*4);
  int*   flag   = (int*)  alloc(256);
  int*   bcur   = (int*)  alloc((size_t)NBUK*4);
  int2*  gstag  = (int2*) alloc((size_t)NBUK*CAPE*8);   // 14.2 MB fixed-stride staging
  bf16*  wt     = (bf16*) alloc((size_t)3*DD*DD*2);     // 96 KB transposed layer weights
  bf16*  hproj  = (bf16*) alloc((size_t)NN*DD*2);       // 25.6 MB
  bf16*  resid  = (bf16*) alloc((size_t)NN*DD*2);       // 25.6 MB residual stream

  const int NB = (NN + 255)/256; // 391

  k_init<<<NB, 256, 0, stream>>>(gsum, gcnt, bcur, (const unsigned int*)x, flag);
  k_bin<<<NBBIN + 3, 256, 0, stream>>>(srcs, dsts, bcur, gstag, Ws, wt, flag);
  k_bucket<<<NBUK, 256, 0, stream>>>(gstag, bcur, csr, offs, oend);

  const int GEMM_B = (NN + 63)/64;  // 1563

  for (int l=0; l<4; l++){
    if (l == 0){
      k_gemm0<<<NN/4, 128, 0, stream>>>(x, W0, asrc0, adst0, hproj, asrc, adst, flag);
      k_agg<<<NN/4, 256, 0, stream>>>(hproj, asrc, adst, offs, oend, csr, resid,
                                      b0, 0, lng, lnb, 0, flag, 1);
    } else {
      size_t wtoff = (size_t)(l-1)*DD*DD;
      size_t aoff  = (size_t)(l-1)*DD;
      k_gemm_mfma<<<GEMM_B, 256, 0, stream>>>(resid, wt, wtoff,
                                              asrcs, adsts, aoff,
                                              hproj, asrc, adst, flag);
      k_agg<<<NN/4, 256, 0, stream>>>(hproj, asrc, adst, offs, oend, csr, resid,
                                      bs, (size_t)(l-1)*DD, lng, lnb, (size_t)l*DD, flag, 0);
    }
  }

  k_pool<<<(NN+63)/64, 128, 0, stream>>>(resid, d_out, batch, gsum, gcnt, flag);
  k_final<<<(NG*DD+127)/128, 128, 0, stream>>>(gsum, gcnt, d_out, flag);
}

// Round 14
// 635.033 us; speedup vs baseline: 1.3581x; 1.0122x over previous
//
#include <hip/hip_runtime.h>
#include <hip/hip_bf16.h>

#define NN 100000
#define NE 1600000
#define NH 4
#define NC 32
#define DD 128
#define NG 64
#define NIN 7

#define BSH 9                       // bucket = dst >> 9 (512 nodes/bucket)
#define NBUK ((NN + 511) >> BSH)    // 196
#define SEGCAP 9600                 // CSR per-bucket stride (mean 8704, +10 sigma)
#define CAPE (SEGCAP - 512)         // 9088 staged edges/bucket max -> segN <= SEGCAP always
#define CSRN (NBUK * SEGCAP)        // 1881600 csr entries
#define NBBIN ((NE + 4095)/4096)    // 391 binning blocks

typedef __hip_bfloat16 bf16;
typedef __attribute__((ext_vector_type(8))) short short8;
typedef __attribute__((ext_vector_type(4))) float f32x4;
typedef __attribute__((ext_vector_type(2))) float f32x2;

__device__ __forceinline__ float b2f(const bf16 v){ return __bfloat162float(v); }

// flag-steered input load: f32 ? fp32 tensor : bf16 tensor
__device__ __forceinline__ float in_ld(const void* p, size_t i, int f32){
  return f32 ? ((const float*)p)[i] : b2f(((const bf16*)p)[i]);
}

__device__ __forceinline__ unsigned int bfbits(float v){
  bf16 b = __float2bfloat16(v);
  return (unsigned int)(*(unsigned short*)&b);
}

// ---------------- init (+ dtype sniffer in block 0) ----------------
__global__ __launch_bounds__(256) void k_init(float* __restrict__ gsum, int* __restrict__ gcnt,
                                              int* __restrict__ bcur,
                                              const unsigned int* __restrict__ xb, int* __restrict__ flag){
  int i = blockIdx.x*256 + threadIdx.x;
  if (i < NG*DD) gsum[i] = 0.f;
  if (i < NG) gcnt[i] = 0;
  if (i < NBUK) bcur[i] = i * CAPE;          // fixed-stride staging base
  if (blockIdx.x == 0 && threadIdx.x < 64){
    int t = threadIdx.x;
    int pl = 0;
    for (int j = t; j < 512; j += 64){
      float v = __uint_as_float(xb[j]);
      float a = fabsf(v);
      if (v == v && a < 1e6f && a > 1e-10f) pl++;
    }
    #pragma unroll
    for (int off = 32; off > 0; off >>= 1) pl += __shfl_down(pl, off);
    if (t == 0) *flag = (pl >= 384) ? 1 : 0;   // >=75% plausible => fp32
  }
}

// ---------------- Pass 1: bin 4096 edges/block by dst-bucket (+ W-prep tail blocks) ----------------
__global__ __launch_bounds__(256) void k_bin(const int* __restrict__ src, const int* __restrict__ dst,
                                             int* __restrict__ bcur, int2* __restrict__ gstag,
                                             const void* __restrict__ Ws, bf16* __restrict__ WT,
                                             const int* __restrict__ flag){
  if (blockIdx.x >= NBBIN){
    // WT[n][k] = W[k][n], bf16 — 3 layers, one block each
    int l = blockIdx.x - NBBIN;   // 0..2
    int f32 = *flag;              // written by k_init (prior launch, stream-ordered)
    for (int idx = threadIdx.x; idx < DD*DD; idx += 256){
      int n = idx >> 7, k = idx & 127;
      WT[(size_t)l*DD*DD + idx] = __float2bfloat16(in_ld(Ws, (size_t)l*DD*DD + (size_t)k*DD + n, f32));
    }
    return;
  }
  __shared__ int cnt[NBUK], pref[NBUK+1], place[NBUK], gbase[NBUK];
  __shared__ int2 pairs[4096];   // 32 KB
  int tid = threadIdx.x;
  for (int b = tid; b < NBUK; b += 256){ cnt[b]=0; place[b]=0; }
  __syncthreads();
  int e0 = blockIdx.x*4096;
  int s[16], d[16];
  #pragma unroll
  for (int i=0;i<16;i++){
    int e = e0 + i*256 + tid;
    s[i] = 0; d[i] = -1;
    if (e < NE){
      unsigned int us = (unsigned int)src[e]; if (us >= NN) us = 0;   // firewall
      unsigned int ud = (unsigned int)dst[e]; if (ud >= NN) ud = 0;   // firewall
      s[i] = (int)us; d[i] = (int)ud;
      atomicAdd(&cnt[ud>>BSH], 1);
    }
  }
  __syncthreads();
  if (tid == 0){
    int run = 0;
    for (int b=0;b<NBUK;b++){ pref[b] = run; run += cnt[b]; }
    pref[NBUK] = run;
  }
  __syncthreads();
  for (int b = tid; b < NBUK; b += 256){
    if (cnt[b] > 0) gbase[b] = atomicAdd(&bcur[b], cnt[b]);
  }
  __syncthreads();
  #pragma unroll
  for (int i=0;i<16;i++){
    if (d[i] >= 0){
      int b = d[i]>>BSH;
      int lp = atomicAdd(&place[b],1);
      pairs[pref[b]+lp] = make_int2(s[i], d[i]);
    }
  }
  __syncthreads();
  int tot = pref[NBUK];
  for (int j = tid; j < tot; j += 256){
    int2 pr = pairs[j];
    int b = pr.y>>BSH;
    int gidx = gbase[b] + (j - pref[b]);
    // firewall: stay inside bucket b's staging strip
    if (gidx >= b*CAPE && gidx < (b+1)*CAPE) gstag[gidx] = pr;
  }
}

// ---------------- Pass 2: per-bucket count + scan + CSR segment in LDS ----------------
__global__ __launch_bounds__(256) void k_bucket(const int2* __restrict__ gstag,
                                                const int* __restrict__ bcur,
                                                int* __restrict__ csr,
                                                int* __restrict__ offs, int* __restrict__ oend){
  __shared__ int seg[SEGCAP];    // 37.5 KB
  __shared__ int lcnt[512];
  __shared__ int loff[512];
  __shared__ int pscan[256];
  int b = blockIdx.x, tid = threadIdx.x;
  int nstart = b << BSH;
  int nend = min(nstart + 512, NN);
  int nloc = nend - nstart;
  int base = b * SEGCAP;
  int stbase = b * CAPE;
  int ecnt = bcur[b] - stbase;
  ecnt = max(0, min(ecnt, CAPE));
  // counts: 1 (self loop) per valid node
  lcnt[tid]     = (tid < nloc) ? 1 : 0;
  lcnt[tid+256] = (tid+256 < nloc) ? 1 : 0;
  __syncthreads();
  for (int j = tid; j < ecnt; j += 256){
    int2 pr = gstag[stbase + j];
    int ln = pr.y - nstart;
    if (ln < 0 || ln >= nloc) ln = 0;   // firewall
    atomicAdd(&lcnt[ln], 1);
  }
  __syncthreads();
  // scan over 512 via pair-sum + Hillis-Steele on 256
  int c0 = lcnt[2*tid], c1 = lcnt[2*tid+1];
  int pairsum = c0 + c1;
  pscan[tid] = pairsum;
  __syncthreads();
  for (int off=1; off<256; off<<=1){
    int a = (tid >= off) ? pscan[tid-off] : 0;
    __syncthreads();
    pscan[tid] += a;
    __syncthreads();
  }
  int pexcl = pscan[tid] - pairsum;
  loff[2*tid]   = pexcl;
  loff[2*tid+1] = pexcl + c0;
  __syncthreads();
  int segN = pscan[255];
  if (segN > SEGCAP) segN = SEGCAP;     // structurally impossible; firewall
  // write offs/oend, place self loops, reset cursors
  if (tid < nloc){
    offs[nstart + tid] = base + loff[tid];
    oend[nstart + tid] = base + loff[tid] + lcnt[tid];
  }
  if (tid + 256 < nloc){
    offs[nstart + tid + 256] = base + loff[tid+256];
    oend[nstart + tid + 256] = base + loff[tid+256] + lcnt[tid+256];
  }
  __syncthreads();
  if (tid < nloc){ int p = loff[tid]; if (p < SEGCAP) seg[p] = nstart + tid; lcnt[tid] = 1; }
  if (tid + 256 < nloc){ int p = loff[tid+256]; if (p < SEGCAP) seg[p] = nstart + tid + 256; lcnt[tid+256] = 1; }
  __syncthreads();
  for (int j = tid; j < ecnt; j += 256){
    int2 pr = gstag[stbase + j];
    int ln = pr.y - nstart;
    if (ln < 0 || ln >= nloc) ln = 0;
    int p = atomicAdd(&lcnt[ln], 1);
    int idx = loff[ln] + p;
    if (idx >= 0 && idx < SEGCAP) seg[idx] = pr.x;
  }
  __syncthreads();
  for (int j = tid; j < segN; j += 256) csr[base + j] = seg[j];
}

// ---------------- layer-0 projection (IN_DIM=7) + alpha ----------------
__device__ __forceinline__ void alpha_red(float acc, float was, float wad, int d, int n,
                                          float* __restrict__ asrc, float* __restrict__ adst){
  float ps = acc*was, pd = acc*wad;
  #pragma unroll
  for (int off=16; off>0; off>>=1){
    ps += __shfl_down(ps, off, 32);
    pd += __shfl_down(pd, off, 32);
  }
  if ((d & 31) == 0){
    asrc[n*NH + (d>>5)] = ps;
    adst[n*NH + (d>>5)] = pd;
  }
}

__global__ __launch_bounds__(128) void k_gemm0(const void* __restrict__ x, const void* __restrict__ W,
    const void* __restrict__ aws, const void* __restrict__ awd,
    bf16* __restrict__ hproj,
    float* __restrict__ asrc, float* __restrict__ adst, const int* __restrict__ flag){
  int f32 = *flag;
  __shared__ float xr[4][NIN];
  int d = threadIdx.x;
  int n0 = blockIdx.x*4;
  if (d < 4*NIN) xr[d/NIN][d%NIN] = in_ld(x, (size_t)n0*NIN + d, f32);
  __syncthreads();
  float a0=0,a1=0,a2=0,a3=0;
  #pragma unroll
  for (int k=0;k<NIN;k++){
    float w = in_ld(W, (size_t)k*DD + d, f32);
    a0 += xr[0][k]*w; a1 += xr[1][k]*w; a2 += xr[2][k]*w; a3 += xr[3][k]*w;
  }
  hproj[(size_t)(n0+0)*DD+d]=__float2bfloat16(a0);
  hproj[(size_t)(n0+1)*DD+d]=__float2bfloat16(a1);
  hproj[(size_t)(n0+2)*DD+d]=__float2bfloat16(a2);
  hproj[(size_t)(n0+3)*DD+d]=__float2bfloat16(a3);
  float was = in_ld(aws, d, f32), wad = in_ld(awd, d, f32);
  alpha_red(a0, was, wad, d, n0+0, asrc, adst);
  alpha_red(a1, was, wad, d, n0+1, asrc, adst);
  alpha_red(a2, was, wad, d, n0+2, asrc, adst);
  alpha_red(a3, was, wad, d, n0+3, asrc, adst);
}

// ---------------- layers 1..3: MFMA GEMM (64 rows/block) + fused alpha ----------------
// LDS rows padded to 136 elements (272 B): b128 frag reads land 2 lanes/bank (free).
#define LDA 136
#define LDB 136

__global__ __launch_bounds__(256) void k_gemm_mfma(
    const bf16* __restrict__ resid,           // bf16 residual stream in ws
    const bf16* __restrict__ WT, size_t wtoff,
    const void* __restrict__ aws, const void* __restrict__ awd, size_t aoff,
    bf16* __restrict__ hproj,
    float* __restrict__ asrc, float* __restrict__ adst,
    const int* __restrict__ flag)
{
  __shared__ bf16 sA[64*LDA];    // 17.0 KB
  __shared__ bf16 sB[128*LDB];   // 34.0 KB
  int f32 = *flag;
  int t = threadIdx.x;
  int n0 = blockIdx.x*64;

  // stage WT (bf16, [n][k]) -> sB. 128x128 bf16 = 2048 uint4; 16 chunks/row.
  {
    const uint4* srcv = (const uint4*)(WT + wtoff);
    #pragma unroll
    for (int i=0;i<8;i++){
      int u4 = t + 256*i;          // 0..2047
      int row = u4 >> 4, c = u4 & 15;
      *(uint4*)(&sB[row*LDB + c*8]) = srcv[u4];
    }
  }
  // stage A: bf16 residual rows n0..n0+63 -> sA (pure uint4 copy; row = 16 uint4)
  {
    const uint4* av = (const uint4*)resid;
    #pragma unroll
    for (int i=0;i<4;i++){
      int u4 = t + 256*i;          // 0..1023
      int row = u4 >> 4, c = u4 & 15;
      int gr = n0 + row;
      uint4 v = make_uint4(0,0,0,0);
      if (gr < NN) v = av[(size_t)gr*16 + c];
      *(uint4*)(&sA[row*LDA + c*8]) = v;
    }
  }
  __syncthreads();

  int wv = t >> 6, lane = t & 63;
  int m = lane & 15, kq = lane >> 4;      // kq = 0..3
  int rowbase = wv*16;

  f32x4 acc[8];
  #pragma unroll
  for (int nt=0; nt<8; nt++) acc[nt] = (f32x4){0.f,0.f,0.f,0.f};

  #pragma unroll
  for (int ks=0; ks<4; ks++){
    short8 afrag = *(const short8*)(&sA[(rowbase + m)*LDA + ks*32 + kq*8]);
    #pragma unroll
    for (int nt=0; nt<8; nt++){
      short8 bfrag = *(const short8*)(&sB[(nt*16 + m)*LDB + ks*32 + kq*8]);
      acc[nt] = __builtin_amdgcn_mfma_f32_16x16x32_bf16(afrag, bfrag, acc[nt], 0, 0, 0);
    }
  }

  // store C -> hproj (bf16). C/D layout: col = lane&15, row = kq*4 + reg
  #pragma unroll
  for (int reg=0; reg<4; reg++){
    int gr = n0 + rowbase + kq*4 + reg;
    if (gr < NN){
      bf16* dst = hproj + (size_t)gr*DD + m;
      #pragma unroll
      for (int nt=0; nt<8; nt++)
        dst[nt*16] = __float2bfloat16(acc[nt][reg]);
    }
  }

  // fused alpha: per-lane a-vector values at col = nt*16 + m
  float avs[8], avd[8];
  #pragma unroll
  for (int nt=0; nt<8; nt++){
    avs[nt] = in_ld(aws, aoff + nt*16 + m, f32);
    avd[nt] = in_ld(awd, aoff + nt*16 + m, f32);
  }
  #pragma unroll
  for (int h=0; h<4; h++){
    #pragma unroll
    for (int reg=0; reg<4; reg++){
      float ps = acc[2*h][reg]*avs[2*h] + acc[2*h+1][reg]*avs[2*h+1];
      float pd = acc[2*h][reg]*avd[2*h] + acc[2*h+1][reg]*avd[2*h+1];
      #pragma unroll
      for (int off=1; off<16; off<<=1){
        ps += __shfl_xor(ps, off);
        pd += __shfl_xor(pd, off);
      }
      if (m == 0){
        int gr = n0 + rowbase + kq*4 + reg;
        if (gr < NN){
          asrc[gr*NH + h] = ps;
          adst[gr*NH + h] = pd;
        }
      }
    }
  }
}

// ---------------- attention aggregation + LN + ELU + residual ----------------
__device__ __forceinline__ float4 edge_e(const float4 as, const float4 ad){
  float4 l, e;
  l.x = as.x + ad.x; l.y = as.y + ad.y; l.z = as.z + ad.z; l.w = as.w + ad.w;
  l.x = l.x > 0.f ? l.x : 0.2f*l.x;
  l.y = l.y > 0.f ? l.y : 0.2f*l.y;
  l.z = l.z > 0.f ? l.z : 0.2f*l.z;
  l.w = l.w > 0.f ? l.w : 0.2f*l.w;
  l.x = fminf(l.x, 30.f); l.y = fminf(l.y, 30.f);   // firewall: true logits <= ~10
  l.z = fminf(l.z, 30.f); l.w = fminf(l.w, 30.f);
  e.x = __expf(l.x); e.y = __expf(l.y); e.z = __expf(l.z); e.w = __expf(l.w);
  return e;
}

__device__ __forceinline__ float2 hp_ld2(const void* hp, int s, int lane){
  unsigned int hv = ((const unsigned int*)hp)[(size_t)s*64 + lane];
  return make_float2(__uint_as_float(hv << 16), __uint_as_float(hv & 0xFFFF0000u));
}

__global__ __launch_bounds__(256) void k_agg(const bf16* __restrict__ hproj,
    const float* __restrict__ asrc, const float* __restrict__ adst,
    const int* __restrict__ offs, const int* __restrict__ oend, const int* __restrict__ csr,
    bf16* __restrict__ resid,
    const void* __restrict__ bias, size_t boff,
    const void* __restrict__ lng, const void* __restrict__ lnb, size_t lnoff,
    const int* __restrict__ flag, const int first)
{
  __shared__ float s_al[4][256];
  int f32 = *flag;
  int wid = threadIdx.x >> 6, lane = threadIdx.x & 63;
  int n = blockIdx.x*4 + wid;        // NN % 4 == 0
  int beg = offs[n];
  int end = oend[n];
  beg = max(0, min(beg, CSRN));
  end = max(beg, min(end, CSRN));
  int deg = min(end - beg, 1024);    // firewall; true max deg ~50
  const float4 ad = ((const float4*)adst)[n];
  int head = lane >> 4;
  int lane4 = lane << 2;             // byte offset of this lane's dword within a row
  const char* hpB = (const char*)hproj;
  f32x2 ac0 = {0.f,0.f}, ac1 = {0.f,0.f}, ac2 = {0.f,0.f}, ac3 = {0.f,0.f};

  if (deg <= 64){
    float4 e = make_float4(0,0,0,0);
    int sregB = 0;
    if (lane < deg){
      unsigned int us = (unsigned int)csr[beg+lane];
      if (us >= NN) us = 0;          // firewall
      sregB = (int)(us << 8);        // row byte offset (256 B/row)
      float4 as = ((const float4*)asrc)[us];
      e = edge_e(as, ad);
    }
    float4 zs = e;
    #pragma unroll
    for (int off=32; off>0; off>>=1){
      zs.x += __shfl_down(zs.x, off);
      zs.y += __shfl_down(zs.y, off);
      zs.z += __shfl_down(zs.z, off);
      zs.w += __shfl_down(zs.w, off);
    }
    float4 invz;
    invz.x = 1.f/(__shfl(zs.x,0)+1e-16f);
    invz.y = 1.f/(__shfl(zs.y,0)+1e-16f);
    invz.z = 1.f/(__shfl(zs.z,0)+1e-16f);
    invz.w = 1.f/(__shfl(zs.w,0)+1e-16f);
    if (lane < deg){
      s_al[wid][lane*4+0] = e.x*invz.x;
      s_al[wid][lane*4+1] = e.y*invz.y;
      s_al[wid][lane*4+2] = e.z*invz.z;
      s_al[wid][lane*4+3] = e.w*invz.w;
    }
    __threadfence_block();
    // unrolled x4: pre-scaled byte offsets, packed f32x2 FMA, 4 loads in flight
    int t = 0;
    for (; t+4 <= deg; t += 4){
      unsigned int o0 = (unsigned int)__shfl(sregB, t+0) + lane4;
      unsigned int o1 = (unsigned int)__shfl(sregB, t+1) + lane4;
      unsigned int o2 = (unsigned int)__shfl(sregB, t+2) + lane4;
      unsigned int o3 = (unsigned int)__shfl(sregB, t+3) + lane4;
      unsigned int h0 = *(const unsigned int*)(hpB + o0);
      unsigned int h1 = *(const unsigned int*)(hpB + o1);
      unsigned int h2 = *(const unsigned int*)(hpB + o2);
      unsigned int h3 = *(const unsigned int*)(hpB + o3);
      float al0 = s_al[wid][(t+0)*4+head];
      float al1 = s_al[wid][(t+1)*4+head];
      float al2 = s_al[wid][(t+2)*4+head];
      float al3 = s_al[wid][(t+3)*4+head];
      f32x2 v0 = {__uint_as_float(h0 << 16), __uint_as_float(h0 & 0xFFFF0000u)};
      f32x2 v1 = {__uint_as_float(h1 << 16), __uint_as_float(h1 & 0xFFFF0000u)};
      f32x2 v2 = {__uint_as_float(h2 << 16), __uint_as_float(h2 & 0xFFFF0000u)};
      f32x2 v3 = {__uint_as_float(h3 << 16), __uint_as_float(h3 & 0xFFFF0000u)};
      ac0 += v0 * al0;
      ac1 += v1 * al1;
      ac2 += v2 * al2;
      ac3 += v3 * al3;
    }
    for (; t < deg; t++){
      unsigned int o = (unsigned int)__shfl(sregB, t) + lane4;
      unsigned int h = *(const unsigned int*)(hpB + o);
      float a = s_al[wid][t*4+head];
      f32x2 v = {__uint_as_float(h << 16), __uint_as_float(h & 0xFFFF0000u)};
      ac0 += v * a;
    }
  } else {
    // general path (cold)
    float4 zs = make_float4(0,0,0,0);
    for (int j=lane; j<deg; j+=64){
      unsigned int us = (unsigned int)csr[beg+j];
      if (us >= NN) us = 0;
      float4 as = ((const float4*)asrc)[us];
      float4 e = edge_e(as, ad);
      zs.x+=e.x; zs.y+=e.y; zs.z+=e.z; zs.w+=e.w;
    }
    #pragma unroll
    for (int off=32; off>0; off>>=1){
      zs.x += __shfl_down(zs.x, off);
      zs.y += __shfl_down(zs.y, off);
      zs.z += __shfl_down(zs.z, off);
      zs.w += __shfl_down(zs.w, off);
    }
    float4 invz;
    invz.x = 1.f/(__shfl(zs.x,0)+1e-16f);
    invz.y = 1.f/(__shfl(zs.y,0)+1e-16f);
    invz.z = 1.f/(__shfl(zs.z,0)+1e-16f);
    invz.w = 1.f/(__shfl(zs.w,0)+1e-16f);
    int nch = (deg+63)>>6;
    for (int c2=0;c2<nch;c2++){
      int base = c2<<6, j = base+lane;
      int sreg = 0;
      __threadfence_block();
      if (j < deg){
        unsigned int us = (unsigned int)csr[beg+j];
        if (us >= NN) us = 0;
        sreg = (int)us;
        float4 as = ((const float4*)asrc)[us];
        float4 e = edge_e(as, ad);
        s_al[wid][lane*4+0]=e.x*invz.x;
        s_al[wid][lane*4+1]=e.y*invz.y;
        s_al[wid][lane*4+2]=e.z*invz.z;
        s_al[wid][lane*4+3]=e.w*invz.w;
      }
      __threadfence_block();
      int cnt = min(64, deg-base);
      for (int t=0;t<cnt;t++){
        int s = __shfl(sreg, t);
        float a = s_al[wid][t*4+head];
        float2 hv = hp_ld2(hproj, s, lane);
        ac0.x += hv.x*a;
        ac0.y += hv.y*a;
      }
    }
  }

  f32x2 accv = (ac0 + ac1) + (ac2 + ac3);
  float2 acc = make_float2(accv.x, accv.y);

  // epilogue: bias + layernorm + elu + residual (residual stream is bf16 in ws)
  float vx = acc.x + in_ld(bias, boff + 2*lane,   f32);
  float vy = acc.y + in_ld(bias, boff + 2*lane+1, f32);
  float s1 = vx+vy, s2 = vx*vx+vy*vy;
  #pragma unroll
  for (int off=32; off>0; off>>=1){
    s1 += __shfl_down(s1, off);
    s2 += __shfl_down(s2, off);
  }
  float mean = __shfl(s1,0) * (1.f/DD);
  float msq  = __shfl(s2,0) * (1.f/DD);
  float var  = fmaxf(msq - mean*mean, 0.f);
  float r = rsqrtf(var + 1e-5f);
  float yx = (vx-mean)*r*in_ld(lng, lnoff+2*lane,   f32) + in_ld(lnb, lnoff+2*lane,   f32);
  float yy = (vy-mean)*r*in_ld(lng, lnoff+2*lane+1, f32) + in_ld(lnb, lnoff+2*lane+1, f32);
  yx = yx>0.f ? yx : expm1f(yx);
  yy = yy>0.f ? yy : expm1f(yy);
  float2 res;
  if (first){
    res = make_float2(yx, yy);
  } else {
    unsigned int pu = ((const unsigned int*)resid)[(size_t)n*64 + lane];
    res = make_float2(__uint_as_float(pu << 16) + yx,
                      __uint_as_float(pu & 0xFFFF0000u) + yy);
  }
  unsigned int pk = bfbits(res.x) | (bfbits(res.y) << 16);
  ((unsigned int*)resid)[(size_t)n*64 + lane] = pk;
}

// ---------------- pooling (reads bf16 residual, writes node embeddings to d_out) ----------------
__global__ __launch_bounds__(128) void k_pool(const bf16* __restrict__ resid, void* __restrict__ dout,
    const int* __restrict__ batch, float* __restrict__ gsum, int* __restrict__ gcnt,
    const int* __restrict__ flag){
  __shared__ int sb[64];
  int f32 = *flag;
  int d = threadIdx.x;
  int n0 = blockIdx.x*64;
  int cnt = min(64, NN - n0);
  if (d < cnt){
    unsigned int b = (unsigned int)batch[n0 + d];
    if (b >= NG) b = 0;            // firewall
    sb[d] = (int)b;
  }
  __syncthreads();
  float local = 0.f;
  int cur = sb[0];
  for (int i=0;i<cnt;i++){
    int b = sb[i];
    if (b != cur){
      atomicAdd(&gsum[cur*DD + d], local);
      local = 0.f; cur = b;
    }
    size_t idx = (size_t)(n0+i)*DD + d;
    float v = b2f(resid[idx]);
    if (f32) ((float*)dout)[idx] = v;
    else     ((bf16*)dout)[idx] = resid[idx];
    local += v;
  }
  atomicAdd(&gsum[cur*DD + d], local);
  if (d == 0){
    int lc = 0; int c2 = sb[0];
    for (int i=0;i<cnt;i++){
      int b = sb[i];
      if (b != c2){ atomicAdd(&gcnt[c2], lc); lc = 0; c2 = b; }
      lc++;
    }
    atomicAdd(&gcnt[c2], lc);
  }
}

__global__ __launch_bounds__(128) void k_final(const float* __restrict__ gsum, const int* __restrict__ gcnt,
                                               void* __restrict__ dout, const int* __restrict__ flag){
  int f32 = *flag;
  int i = blockIdx.x*128 + threadIdx.x;
  if (i < NG*DD){
    float c = (float)gcnt[i>>7];
    if (c < 1.f) c = 1.f;
    float val = gsum[i] / c;
    if (f32) ((float*)dout)[(size_t)NN*DD + i] = val;
    else     ((bf16*)dout)[(size_t)NN*DD + i] = __float2bfloat16(val);
  }
}

extern "C" void kernel_launch(void* const* d_in, const int* in_sizes, int n_in,
                              void* d_out, int out_size, void* d_ws, size_t ws_size,
                              hipStream_t stream){
  const void* x      = d_in[0];
  const int*  ei     = (const int*) d_in[1];
  const int*  batch  = (const int*) d_in[2];
  const void* W0     = d_in[3];
  const void* asrc0  = d_in[4];
  const void* adst0  = d_in[5];
  const void* b0     = d_in[6];
  const void* Ws     = d_in[7];
  const void* asrcs  = d_in[8];
  const void* adsts  = d_in[9];
  const void* bs     = d_in[10];
  const void* lng    = d_in[11];
  const void* lnb    = d_in[12];

  const int* srcs = ei;
  const int* dsts = ei + NE;

  uintptr_t p0 = (uintptr_t)d_ws;
  uintptr_t p = p0;
  auto alloc = [&](size_t bytes)->void* {
    void* r = (void*)p; p += (bytes + 255) & ~(size_t)255; return r;
  };
  int*   csr    = (int*)  alloc((size_t)CSRN*4);        // 7.5 MB fixed-stride CSR
  int*   offs   = (int*)  alloc((size_t)NN*4);
  int*   oend   = (int*)  alloc((size_t)NN*4);
  float* asrc   = (float*)alloc((size_t)NN*NH*4);
  float* adst   = (float*)alloc((size_t)NN*NH*4);
  float* gsum   = (float*)alloc((size_t)NG*DD*4);
  int*   gcnt   = (int*)  alloc(NG*4);
  int*   flag   = (int*)  alloc(256);
  int*   bcur   = (int*)  alloc((size_t)NBUK*4);
  int2*  gstag  = (int2*) alloc((size_t)NBUK*CAPE*8);   // 14.2 MB fixed-stride staging
  bf16*  wt     = (bf16*) alloc((size_t)3*DD*DD*2);     // 96 KB transposed layer weights
  bf16*  hproj  = (bf16*) alloc((size_t)NN*DD*2);       // 25.6 MB
  bf16*  resid  = (bf16*) alloc((size_t)NN*DD*2);       // 25.6 MB residual stream

  const int NB = (NN + 255)/256; // 391

  k_init<<<NB, 256, 0, stream>>>(gsum, gcnt, bcur, (const unsigned int*)x, flag);
  k_bin<<<NBBIN + 3, 256, 0, stream>>>(srcs, dsts, bcur, gstag, Ws, wt, flag);
  k_bucket<<<NBUK, 256, 0, stream>>>(gstag, bcur, csr, offs, oend);

  const int GEMM_B = (NN + 63)/64;  // 1563

  for (int l=0; l<4; l++){
    if (l == 0){
      k_gemm0<<<NN/4, 128, 0, stream>>>(x, W0, asrc0, adst0, hproj, asrc, adst, flag);
      k_agg<<<NN/4, 256, 0, stream>>>(hproj, asrc, adst, offs, oend, csr, resid,
                                      b0, 0, lng, lnb, 0, flag, 1);
    } else {
      size_t wtoff = (size_t)(l-1)*DD*DD;
      size_t aoff  = (size_t)(l-1)*DD;
      k_gemm_mfma<<<GEMM_B, 256, 0, stream>>>(resid, wt, wtoff,
                                              asrcs, adsts, aoff,
                                              hproj, asrc, adst, flag);
      k_agg<<<NN/4, 256, 0, stream>>>(hproj, asrc, adst, offs, oend, csr, resid,
                                      bs, (size_t)(l-1)*DD, lng, lnb, (size_t)l*DD, flag, 0);
    }
  }

  k_pool<<<(NN+63)/64, 128, 0, stream>>>(resid, d_out, batch, gsum, gcnt, flag);
  k_final<<<(NG*DD+127)/128, 128, 0, stream>>>(gsum, gcnt, d_out, flag);
}